// Round 4
// baseline (7467.434 us; speedup 1.0000x reference)
//
#include <hip/hip_runtime.h>
#include <math.h>

// ---------------- problem constants ----------------
#define BB     32
#define NN     64
#define DIMM   512
#define HEADS  4
#define DH     128
#define FFD    2048
#define JJ     2048          // kv length per batch (B*N)
#define RX     2048          // B*N rows (x path)
#define RCTX   65536         // B*J rows (context path)
#define TOPKK  64
#define CH     4096          // context chunk rows
#define NCH    16

#define M_SWISH   0
#define M_RESHALF 1
#define M_Q       2
#define M_KV      3
#define M_RESBIAS 4

#define FLTMAXF 3.402823466e38f

// total workspace floats required (see kernel_launch layout)
#define WS_FLOATS_REQ 89128960ull   // = 356,515,840 bytes

__device__ __forceinline__ float wred_sum(float v) {
    #pragma unroll
    for (int m = 1; m < 64; m <<= 1) v += __shfl_xor(v, m, 64);
    return v;
}
__device__ __forceinline__ int wred_sumi(int v) {
    #pragma unroll
    for (int m = 1; m < 64; m <<= 1) v += __shfl_xor(v, m, 64);
    return v;
}
__device__ __forceinline__ float wred_max(float v) {
    #pragma unroll
    for (int m = 1; m < 64; m <<= 1) v = fmaxf(v, __shfl_xor(v, m, 64));
    return v;
}

// order-preserving float -> uint key (ascending)
__device__ __forceinline__ unsigned fkey(float f) {
    unsigned u = __float_as_uint(f);
    return (u & 0x80000000u) ? ~u : (u | 0x80000000u);
}

// ---------------- LayerNorm over rows of length 512 ----------------
// one wave per row; block = 4 waves
__global__ __launch_bounds__(256) void ln_k(const float* __restrict__ in,
                                            const float* __restrict__ gam,
                                            const float* __restrict__ bet,
                                            float* __restrict__ out)
{
    const int row  = blockIdx.x * 4 + (threadIdx.x >> 6);
    const int lane = threadIdx.x & 63;
    const float* p = in + (size_t)row * DIMM + lane * 8;

    float a[8];
    *(float4*)&a[0] = *(const float4*)p;
    *(float4*)&a[4] = *(const float4*)(p + 4);

    float s = 0.f;
    #pragma unroll
    for (int i = 0; i < 8; ++i) s += a[i];
    s = wred_sum(s);
    const float mean = s * (1.0f / DIMM);

    float vs = 0.f;
    #pragma unroll
    for (int i = 0; i < 8; ++i) { float d = a[i] - mean; vs += d * d; }
    vs = wred_sum(vs);
    const float var = vs * (1.0f / DIMM) + 1e-5f;
    float r = rsqrtf(var);
    r = r * (1.5f - 0.5f * var * r * r);   // Newton refine

    float g[8], b[8];
    *(float4*)&g[0] = *(const float4*)(gam + lane * 8);
    *(float4*)&g[4] = *(const float4*)(gam + lane * 8 + 4);
    *(float4*)&b[0] = *(const float4*)(bet + lane * 8);
    *(float4*)&b[4] = *(const float4*)(bet + lane * 8 + 4);

    float o[8];
    #pragma unroll
    for (int i = 0; i < 8; ++i) o[i] = g[i] * (a[i] - mean) * r + b[i];

    float* q = out + (size_t)row * DIMM + lane * 8;
    *(float4*)q       = *(float4*)&o[0];
    *(float4*)(q + 4) = *(float4*)&o[4];
}

// ---------------- generic f32 GEMM: out = epilogue(A[M,K] @ W[K,N] + bias) ----------------
// tile 128x128, BK=32, 256 threads, 8x8 per thread
// launch_bounds (256,2): 2 waves/EU -> <=256 VGPR budget; 8x8 acc + operands
// needs ~140 VGPR, a 128-cap (4 waves/EU) would risk inner-loop spills.
template<int MODE>
__global__ __launch_bounds__(256, 2) void gemm_k(const float* __restrict__ A,
                                                 const float* __restrict__ W,
                                                 const float* __restrict__ bias,
                                                 const float* __restrict__ res,
                                                 float* __restrict__ out,
                                                 float* __restrict__ out2,
                                                 int M, int N, int K, int row0)
{
    __shared__ float As[32][132];   // transposed: As[k][m], padded
    __shared__ float Bs[32][128];

    const int tid = threadIdx.x;
    const int bm = blockIdx.y * 128;
    const int bn = blockIdx.x * 128;
    const int ty = tid >> 4;   // 0..15 -> rows ty*8 .. ty*8+7
    const int tx = tid & 15;   // cols tx*4..+3 and tx*4+64..+67

    float acc[8][8];
    #pragma unroll
    for (int i = 0; i < 8; ++i)
        #pragma unroll
        for (int j = 0; j < 8; ++j) acc[i][j] = 0.f;

    for (int k0 = 0; k0 < K; k0 += 32) {
        __syncthreads();
        // stage A tile (128 rows x 32 k), transposed into As[k][m]
        #pragma unroll
        for (int q = 0; q < 4; ++q) {
            const int s  = tid + 256 * q;
            const int r  = s >> 3;        // 0..127
            const int kq = s & 7;         // 0..7
            const float4 v = *(const float4*)(A + (size_t)(bm + r) * K + k0 + kq * 4);
            As[kq * 4 + 0][r] = v.x;
            As[kq * 4 + 1][r] = v.y;
            As[kq * 4 + 2][r] = v.z;
            As[kq * 4 + 3][r] = v.w;
        }
        // stage B tile (32 k x 128 n)
        #pragma unroll
        for (int q = 0; q < 4; ++q) {
            const int s  = tid + 256 * q;
            const int kk = s >> 5;        // 0..31
            const int cq = s & 31;        // 0..31
            *(float4*)&Bs[kk][cq * 4] = *(const float4*)(W + (size_t)(k0 + kk) * N + bn + cq * 4);
        }
        __syncthreads();
        #pragma unroll
        for (int kk = 0; kk < 32; ++kk) {
            float a[8], b[8];
            *(float4*)&a[0] = *(const float4*)&As[kk][ty * 8];
            *(float4*)&a[4] = *(const float4*)&As[kk][ty * 8 + 4];
            *(float4*)&b[0] = *(const float4*)&Bs[kk][tx * 4];
            *(float4*)&b[4] = *(const float4*)&Bs[kk][tx * 4 + 64];
            #pragma unroll
            for (int i = 0; i < 8; ++i)
                #pragma unroll
                for (int j = 0; j < 8; ++j)
                    acc[i][j] = fmaf(a[i], b[j], acc[i][j]);
        }
    }

    // epilogue
    #pragma unroll
    for (int i = 0; i < 8; ++i) {
        const int r = bm + ty * 8 + i;
        #pragma unroll
        for (int jg = 0; jg < 2; ++jg) {
            const int c = bn + tx * 4 + jg * 64;
            float o[4];
            o[0] = acc[i][jg * 4 + 0]; o[1] = acc[i][jg * 4 + 1];
            o[2] = acc[i][jg * 4 + 2]; o[3] = acc[i][jg * 4 + 3];
            float bi[4];
            *(float4*)&bi[0] = *(const float4*)(bias + c);

            if (MODE == M_SWISH) {
                #pragma unroll
                for (int e = 0; e < 4; ++e) {
                    float v = o[e] + bi[e];
                    o[e] = v / (1.f + expf(-v));
                }
                *(float4*)(out + (size_t)r * N + c) = *(float4*)&o[0];
            } else if (MODE == M_RESHALF) {
                float rv[4];
                *(float4*)&rv[0] = *(const float4*)(res + (size_t)r * N + c);
                #pragma unroll
                for (int e = 0; e < 4; ++e) o[e] = rv[e] + 0.5f * (o[e] + bi[e]);
                *(float4*)(out + (size_t)r * N + c) = *(float4*)&o[0];
            } else if (MODE == M_RESBIAS) {
                float rv[4];
                *(float4*)&rv[0] = *(const float4*)(res + (size_t)r * N + c);
                #pragma unroll
                for (int e = 0; e < 4; ++e) o[e] = rv[e] + o[e] + bi[e];
                *(float4*)(out + (size_t)r * N + c) = *(float4*)&o[0];
            } else if (MODE == M_Q) {
                #pragma unroll
                for (int e = 0; e < 4; ++e) o[e] += bi[e];
                const int b_ = r >> 6, i_ = r & 63, h_ = c >> 7, d_ = c & 127;
                *(float4*)(out + (((size_t)(b_ * HEADS + h_) * NN + i_) * DH + d_)) = *(float4*)&o[0];
            } else if (MODE == M_KV) {
                #pragma unroll
                for (int e = 0; e < 4; ++e) o[e] += bi[e];
                const int grow = row0 + r;
                const int b_ = grow >> 11, j_ = grow & 2047;
                float* dst = out;
                int cc = c;
                if (c >= 512) { cc = c - 512; dst = out2; }
                const int h_ = cc >> 7, d_ = cc & 127;
                *(float4*)(dst + (((size_t)(b_ * HEADS + h_) * JJ + j_) * DH + d_)) = *(float4*)&o[0];
            }
        }
    }
}

// ---------------- dots = scale * Q @ K^T, per (b,h) ----------------
// grid: (J/128, B*H); block 256; per-thread 4 rows x 8 cols; K-dim(d)=128 in 32-chunks
__global__ __launch_bounds__(256) void dots_k(const float* __restrict__ Q,
                                              const float* __restrict__ Kb,
                                              float* __restrict__ dots)
{
    __shared__ float Qs[32][68];
    __shared__ float Ks[32][132];
    const int bh = blockIdx.y;
    const int jt = blockIdx.x * 128;
    const float* Qp = Q  + (size_t)bh * NN * DH;
    const float* Kp = Kb + (size_t)bh * JJ * DH;
    const int tid = threadIdx.x;
    const int ty = tid >> 4;   // 0..15 -> rows ty*4..+3
    const int tx = tid & 15;   // cols tx*4, tx*4+64

    float acc[4][8];
    #pragma unroll
    for (int i = 0; i < 4; ++i)
        #pragma unroll
        for (int j = 0; j < 8; ++j) acc[i][j] = 0.f;

    for (int d0 = 0; d0 < DH; d0 += 32) {
        __syncthreads();
        #pragma unroll
        for (int q = 0; q < 2; ++q) {            // Q tile 64x32
            const int s = tid + 256 * q;
            const int i = s >> 3, dq = s & 7;
            const float4 v = *(const float4*)(Qp + (size_t)i * DH + d0 + dq * 4);
            Qs[dq * 4 + 0][i] = v.x; Qs[dq * 4 + 1][i] = v.y;
            Qs[dq * 4 + 2][i] = v.z; Qs[dq * 4 + 3][i] = v.w;
        }
        #pragma unroll
        for (int q = 0; q < 4; ++q) {            // K tile 128x32 (transposed)
            const int s = tid + 256 * q;
            const int j = s >> 3, dq = s & 7;
            const float4 v = *(const float4*)(Kp + (size_t)(jt + j) * DH + d0 + dq * 4);
            Ks[dq * 4 + 0][j] = v.x; Ks[dq * 4 + 1][j] = v.y;
            Ks[dq * 4 + 2][j] = v.z; Ks[dq * 4 + 3][j] = v.w;
        }
        __syncthreads();
        #pragma unroll
        for (int d = 0; d < 32; ++d) {
            float a[4], b[8];
            *(float4*)&a[0] = *(const float4*)&Qs[d][ty * 4];
            *(float4*)&b[0] = *(const float4*)&Ks[d][tx * 4];
            *(float4*)&b[4] = *(const float4*)&Ks[d][tx * 4 + 64];
            #pragma unroll
            for (int i = 0; i < 4; ++i)
                #pragma unroll
                for (int j = 0; j < 8; ++j)
                    acc[i][j] = fmaf(a[i], b[j], acc[i][j]);
        }
    }

    const float scl = 0.08838834764831845f;   // 128^-0.5
    #pragma unroll
    for (int i = 0; i < 4; ++i) {
        const int row = ty * 4 + i;
        #pragma unroll
        for (int jg = 0; jg < 2; ++jg) {
            const int c = tx * 4 + jg * 64;
            float o[4];
            #pragma unroll
            for (int e = 0; e < 4; ++e) o[e] = acc[i][jg * 4 + e] * scl;
            *(float4*)(dots + ((size_t)bh * NN + row) * JJ + jt + c) = *(float4*)&o[0];
        }
    }
}

// ---------------- exact top-k threshold + masked softmax; overwrites dots with weights ----------------
// one wave per row; block = 4 waves
__global__ __launch_bounds__(256) void topk_sm_k(float* __restrict__ dots)
{
    const int wid  = threadIdx.x >> 6;
    const int lane = threadIdx.x & 63;
    const int r = blockIdx.x * 4 + wid;          // 0..8191 = (b*4+h)*64+i
    const int b = r >> 8;
    const int h = (r >> 6) & 3;
    float* row = dots + (size_t)r * JJ;

    float d[32];
    unsigned key[32];
    #pragma unroll
    for (int t = 0; t < 32; ++t) {
        d[t] = row[lane + 64 * t];
        key[t] = fkey(d[t]);
    }

    // binary search (MSB-first) for key of TOPK-th largest value:
    // finds max cur with count(key >= cur) >= TOPK  ==>  cur = key of k-th largest
    unsigned cur = 0u;
    for (int bit = 31; bit >= 0; --bit) {
        const unsigned cand = cur | (1u << bit);
        int c = 0;
        #pragma unroll
        for (int t = 0; t < 32; ++t) c += (key[t] >= cand) ? 1 : 0;
        c = wred_sumi(c);
        if (c >= TOPKK) cur = cand;
    }

    // local mask per head + threshold; masked -> -FLT_MAX
    const int LB = (h == 0) ? 1 : (h == 1) ? 4 : (h == 2) ? 8 : 1000;
    float m = -FLTMAXF;
    #pragma unroll
    for (int t = 0; t < 32; ++t) {
        const int j = lane + 64 * t;
        int df = (j >> 6) - b; df = (df < 0) ? -df : df;
        const bool keep = (df <= LB) && (key[t] >= cur);
        d[t] = keep ? d[t] : -FLTMAXF;
        m = fmaxf(m, d[t]);
    }
    m = wred_max(m);

    float s = 0.f;
    float e[32];
    #pragma unroll
    for (int t = 0; t < 32; ++t) {
        e[t] = expf(d[t] - m);   // all-masked row: m=-FLT_MAX -> exp(0)=1 -> uniform (matches ref)
        s += e[t];
    }
    s = wred_sum(s);
    const float inv = 1.0f / s;

    #pragma unroll
    for (int t = 0; t < 32; ++t) row[lane + 64 * t] = e[t] * inv;
}

// ---------------- attn_out = W @ V per (b,h), scatter to [B*N, INNER] ----------------
// grid: (B*H, 2); block 256; per-thread 4 rows x 4 cols (2+2 split)
__global__ __launch_bounds__(256) void pv_k(const float* __restrict__ Wt,
                                            const float* __restrict__ Vb,
                                            float* __restrict__ attn)
{
    __shared__ float Ws[32][36];
    __shared__ float Vs[32][128];
    const int bh = blockIdx.x;
    const int half = blockIdx.y;
    const float* Wp = Wt + (size_t)bh * NN * JJ + (size_t)half * 32 * JJ;
    const float* Vp = Vb + (size_t)bh * JJ * DH;
    const int tid = threadIdx.x;
    const int ty = tid >> 5;   // 0..7 -> rows ty*4..+3 (of 32)
    const int tx = tid & 31;   // cols tx*2, tx*2+64

    float acc[4][4];
    #pragma unroll
    for (int i = 0; i < 4; ++i)
        #pragma unroll
        for (int j = 0; j < 4; ++j) acc[i][j] = 0.f;

    for (int j0 = 0; j0 < JJ; j0 += 32) {
        __syncthreads();
        {   // W tile 32 rows x 32 j, transposed
            const int i = tid >> 3, jq = tid & 7;
            const float4 v = *(const float4*)(Wp + (size_t)i * JJ + j0 + jq * 4);
            Ws[jq * 4 + 0][i] = v.x; Ws[jq * 4 + 1][i] = v.y;
            Ws[jq * 4 + 2][i] = v.z; Ws[jq * 4 + 3][i] = v.w;
        }
        #pragma unroll
        for (int q = 0; q < 4; ++q) {    // V tile 32 j x 128 d
            const int s = tid + 256 * q;
            const int j = s >> 5, dq = s & 31;
            *(float4*)&Vs[j][dq * 4] = *(const float4*)(Vp + (size_t)(j0 + j) * DH + dq * 4);
        }
        __syncthreads();
        #pragma unroll
        for (int j = 0; j < 32; ++j) {
            float a[4], bb[4];
            *(float4*)&a[0] = *(const float4*)&Ws[j][ty * 4];
            bb[0] = Vs[j][tx * 2];      bb[1] = Vs[j][tx * 2 + 1];
            bb[2] = Vs[j][tx * 2 + 64]; bb[3] = Vs[j][tx * 2 + 65];
            #pragma unroll
            for (int i = 0; i < 4; ++i)
                #pragma unroll
                for (int jj = 0; jj < 4; ++jj)
                    acc[i][jj] = fmaf(a[i], bb[jj], acc[i][jj]);
        }
    }

    const int b = bh >> 2, h = bh & 3;
    #pragma unroll
    for (int i = 0; i < 4; ++i) {
        const int row = b * NN + half * 32 + ty * 4 + i;
        const size_t base = (size_t)row * DIMM + h * DH;
        *(float2*)(attn + base + tx * 2)      = make_float2(acc[i][0], acc[i][1]);
        *(float2*)(attn + base + 64 + tx * 2) = make_float2(acc[i][2], acc[i][3]);
    }
}

// ---------------- host ----------------
extern "C" void kernel_launch(void* const* d_in, const int* in_sizes, int n_in,
                              void* d_out, int out_size, void* d_ws, size_t ws_size,
                              hipStream_t stream)
{
    // Safety guard: if the provided workspace is smaller than our layout
    // requires, launching would write OOB (and can wedge the node). Instead,
    // do nothing -> harness reports a clean validation failure with logs,
    // which tells us ws_size is the problem. Free when ws is ample.
    if (ws_size < WS_FLOATS_REQ * sizeof(float)) return;

    const float* x       = (const float*)d_in[0];
    const float* ctx     = (const float*)d_in[1];
    const float* ff1_w1  = (const float*)d_in[2];
    const float* ff1_b1  = (const float*)d_in[3];
    const float* ff1_w2  = (const float*)d_in[4];
    const float* ff1_b2  = (const float*)d_in[5];
    const float* ffkv_w1 = (const float*)d_in[6];
    const float* ffkv_b1 = (const float*)d_in[7];
    const float* ffkv_w2 = (const float*)d_in[8];
    const float* ffkv_b2 = (const float*)d_in[9];
    const float* wq      = (const float*)d_in[10];
    const float* bq      = (const float*)d_in[11];
    const float* wkv     = (const float*)d_in[12];
    const float* bkv     = (const float*)d_in[13];
    const float* wo      = (const float*)d_in[14];
    const float* bo      = (const float*)d_in[15];
    const float* ln1_g   = (const float*)d_in[16];
    const float* ln1_b   = (const float*)d_in[17];
    const float* lnkv_g  = (const float*)d_in[18];
    const float* lnkv_b  = (const float*)d_in[19];
    const float* lna_g   = (const float*)d_in[20];
    const float* lna_b   = (const float*)d_in[21];
    const float* lnf_g   = (const float*)d_in[22];
    const float* lnf_b   = (const float*)d_in[23];

    float* ws = (float*)d_ws;
    float* qb   = ws;                              // [B,H,N,DH]      1,048,576
    float* Kb   = qb  + (size_t)1048576;           // [B,H,J,DH]     33,554,432
    float* Vb   = Kb  + (size_t)33554432;          //                33,554,432
    float* R    = Vb  + (size_t)33554432;          // union region   16,777,216
    float* x1   = R   + (size_t)16777216;          //                 1,048,576
    float* lnx  = x1  + (size_t)1048576;           //                 1,048,576
    float* attn = lnx + (size_t)1048576;           //                 1,048,576
    float* x2   = attn+ (size_t)1048576;           //                 1,048,576
    // union-region overlays (temporally disjoint):
    float* hx   = R;                   // x-path hidden   [2048,2048]
    float* lnc  = R;                   // chunk LN        [CH,512]
    float* hc   = R + (size_t)2097152; // chunk hidden    [CH,2048]
    float* ctxn = R + (size_t)10485760;// chunk ctx_new   [CH,512]
    float* dots = R;                   // attention       [B*H*N, J]

    // ---- x path: half-step FFN ----
    ln_k<<<RX / 4, 256, 0, stream>>>(x, ln1_g, ln1_b, lnx);
    gemm_k<M_SWISH><<<dim3(FFD / 128, RX / 128), 256, 0, stream>>>(
        lnx, ff1_w1, ff1_b1, nullptr, hx, nullptr, RX, FFD, DIMM, 0);
    gemm_k<M_RESHALF><<<dim3(DIMM / 128, RX / 128), 256, 0, stream>>>(
        hx, ff1_w2, ff1_b2, x, x1, nullptr, RX, DIMM, FFD, 0);

    // ---- q = LN(x1) @ wq + bq ----
    ln_k<<<RX / 4, 256, 0, stream>>>(x1, lna_g, lna_b, lnx);
    gemm_k<M_Q><<<dim3(DIMM / 128, RX / 128), 256, 0, stream>>>(
        lnx, wq, bq, nullptr, qb, nullptr, RX, DIMM, DIMM, 0);

    // ---- context path: half-step FFN + KV projection, chunked ----
    for (int c = 0; c < NCH; ++c) {
        const float* cptr = ctx + (size_t)c * CH * DIMM;
        ln_k<<<CH / 4, 256, 0, stream>>>(cptr, lnkv_g, lnkv_b, lnc);
        gemm_k<M_SWISH><<<dim3(FFD / 128, CH / 128), 256, 0, stream>>>(
            lnc, ffkv_w1, ffkv_b1, nullptr, hc, nullptr, CH, FFD, DIMM, 0);
        gemm_k<M_RESHALF><<<dim3(DIMM / 128, CH / 128), 256, 0, stream>>>(
            hc, ffkv_w2, ffkv_b2, cptr, ctxn, nullptr, CH, DIMM, FFD, 0);
        gemm_k<M_KV><<<dim3(1024 / 128, CH / 128), 256, 0, stream>>>(
            ctxn, wkv, bkv, nullptr, Kb, Vb, CH, 1024, DIMM, c * CH);
    }

    // ---- attention ----
    dots_k<<<dim3(JJ / 128, BB * HEADS), 256, 0, stream>>>(qb, Kb, dots);
    topk_sm_k<<<(BB * HEADS * NN) / 4, 256, 0, stream>>>(dots);
    pv_k<<<dim3(BB * HEADS, 2), 256, 0, stream>>>(dots, Vb, attn);

    // ---- output projection + residual + final LN ----
    gemm_k<M_RESBIAS><<<dim3(DIMM / 128, RX / 128), 256, 0, stream>>>(
        attn, wo, bo, x1, x2, nullptr, RX, DIMM, DIMM, 0);
    ln_k<<<RX / 4, 256, 0, stream>>>(x2, lnf_g, lnf_b, (float*)d_out);
}

// Round 5
// 2945.867 us; speedup vs baseline: 2.5349x; 2.5349x over previous
//
#include <hip/hip_runtime.h>
#include <math.h>

// ---------------- problem constants ----------------
#define BB     32
#define NN     64
#define DIMM   512
#define HEADS  4
#define DH     128
#define FFD    2048
#define JJ     2048
#define RX     2048
#define TOPKK  64
#define CH     4096
#define NCH    16
#define FLTMAXF 3.402823466e38f

// workspace words (4B) required -- see layout in kernel_launch (297.8 MB < proven 356.5 MB)
#define WS_WORDS_REQ 74448896ull

typedef unsigned short u16;
typedef unsigned int   u32;

using f32x4  = __attribute__((ext_vector_type(4))) float;
using short8 = __attribute__((ext_vector_type(8))) short;   // 8 bf16 (4 VGPRs) per guide §3

__device__ __forceinline__ float wred_sum(float v) {
    #pragma unroll
    for (int m = 1; m < 64; m <<= 1) v += __shfl_xor(v, m, 64);
    return v;
}
__device__ __forceinline__ int wred_sumi(int v) {
    #pragma unroll
    for (int m = 1; m < 64; m <<= 1) v += __shfl_xor(v, m, 64);
    return v;
}
__device__ __forceinline__ float wred_max(float v) {
    #pragma unroll
    for (int m = 1; m < 64; m <<= 1) v = fmaxf(v, __shfl_xor(v, m, 64));
    return v;
}
__device__ __forceinline__ unsigned fkey(float f) {
    unsigned u = __float_as_uint(f);
    return (u & 0x80000000u) ? ~u : (u | 0x80000000u);
}

// bf16 split helpers (round-to-nearest-even)
__device__ __forceinline__ u16 bf16rne(float f) {
    u32 u = __float_as_uint(f);
    return (u16)((u + 0x7FFFu + ((u >> 16) & 1u)) >> 16);
}
__device__ __forceinline__ float bf16tof(u16 h) {
    return __uint_as_float(((u32)h) << 16);
}
__device__ __forceinline__ void split2(float f, u16& h, u16& l) {
    h = bf16rne(f);
    l = bf16rne(f - bf16tof(h));
}

// ---------------- LayerNorm (f32 out) ----------------
__global__ __launch_bounds__(256) void ln_k(const float* __restrict__ in,
                                            const float* __restrict__ gam,
                                            const float* __restrict__ bet,
                                            float* __restrict__ out)
{
    const int row  = blockIdx.x * 4 + (threadIdx.x >> 6);
    const int lane = threadIdx.x & 63;
    const float* p = in + (size_t)row * DIMM + lane * 8;

    float a[8];
    *(float4*)&a[0] = *(const float4*)p;
    *(float4*)&a[4] = *(const float4*)(p + 4);

    float s = 0.f;
    #pragma unroll
    for (int i = 0; i < 8; ++i) s += a[i];
    s = wred_sum(s);
    const float mean = s * (1.0f / DIMM);

    float vs = 0.f;
    #pragma unroll
    for (int i = 0; i < 8; ++i) { float d = a[i] - mean; vs += d * d; }
    vs = wred_sum(vs);
    const float var = vs * (1.0f / DIMM) + 1e-5f;
    float r = rsqrtf(var);
    r = r * (1.5f - 0.5f * var * r * r);

    float g[8], b[8];
    *(float4*)&g[0] = *(const float4*)(gam + lane * 8);
    *(float4*)&g[4] = *(const float4*)(gam + lane * 8 + 4);
    *(float4*)&b[0] = *(const float4*)(bet + lane * 8);
    *(float4*)&b[4] = *(const float4*)(bet + lane * 8 + 4);

    float o[8];
    #pragma unroll
    for (int i = 0; i < 8; ++i) o[i] = g[i] * (a[i] - mean) * r + b[i];

    float* q = out + (size_t)row * DIMM + lane * 8;
    *(float4*)q       = *(float4*)&o[0];
    *(float4*)(q + 4) = *(float4*)&o[4];
}

// ---------------- LayerNorm -> split bf16 (hi,lo) out ----------------
__global__ __launch_bounds__(256) void ln_split_k(const float* __restrict__ in,
                                                  const float* __restrict__ gam,
                                                  const float* __restrict__ bet,
                                                  u16* __restrict__ oh,
                                                  u16* __restrict__ ol)
{
    const int row  = blockIdx.x * 4 + (threadIdx.x >> 6);
    const int lane = threadIdx.x & 63;
    const float* p = in + (size_t)row * DIMM + lane * 8;

    float a[8];
    *(float4*)&a[0] = *(const float4*)p;
    *(float4*)&a[4] = *(const float4*)(p + 4);

    float s = 0.f;
    #pragma unroll
    for (int i = 0; i < 8; ++i) s += a[i];
    s = wred_sum(s);
    const float mean = s * (1.0f / DIMM);

    float vs = 0.f;
    #pragma unroll
    for (int i = 0; i < 8; ++i) { float d = a[i] - mean; vs += d * d; }
    vs = wred_sum(vs);
    const float var = vs * (1.0f / DIMM) + 1e-5f;
    float r = rsqrtf(var);
    r = r * (1.5f - 0.5f * var * r * r);

    float g[8], b[8];
    *(float4*)&g[0] = *(const float4*)(gam + lane * 8);
    *(float4*)&g[4] = *(const float4*)(gam + lane * 8 + 4);
    *(float4*)&b[0] = *(const float4*)(bet + lane * 8);
    *(float4*)&b[4] = *(const float4*)(bet + lane * 8 + 4);

    u32 ph[4], pl[4];
    #pragma unroll
    for (int i = 0; i < 4; ++i) {
        float o0 = g[2*i]   * (a[2*i]   - mean) * r + b[2*i];
        float o1 = g[2*i+1] * (a[2*i+1] - mean) * r + b[2*i+1];
        u16 h0, l0, h1, l1;
        split2(o0, h0, l0);
        split2(o1, h1, l1);
        ph[i] = (u32)h0 | ((u32)h1 << 16);
        pl[i] = (u32)l0 | ((u32)l1 << 16);
    }
    uint4 vh; vh.x = ph[0]; vh.y = ph[1]; vh.z = ph[2]; vh.w = ph[3];
    uint4 vl; vl.x = pl[0]; vl.y = pl[1]; vl.z = pl[2]; vl.w = pl[3];
    *(uint4*)(oh + (size_t)row * DIMM + lane * 8) = vh;
    *(uint4*)(ol + (size_t)row * DIMM + lane * 8) = vl;
}

// ---------------- weight transpose + split: W[K][N] f32 -> T[N][K] (hi,lo) bf16 ----------------
__global__ __launch_bounds__(256) void wsplit_k(const float* __restrict__ W,
                                                u16* __restrict__ Th, u16* __restrict__ Tl,
                                                int K, int N)
{
    __shared__ float t[64][65];
    const int k0 = blockIdx.y * 64, n0 = blockIdx.x * 64;
    const int tid = threadIdx.x;
    #pragma unroll
    for (int p = 0; p < 16; ++p) {
        const int idx = p * 256 + tid;
        const int r = idx >> 6, c = idx & 63;
        t[r][c] = W[(size_t)(k0 + r) * N + n0 + c];
    }
    __syncthreads();
    #pragma unroll
    for (int p = 0; p < 16; ++p) {
        const int idx = p * 256 + tid;
        const int r = idx >> 6, c = idx & 63;      // r: n, c: k
        float v = t[c][r];
        u16 h, l; split2(v, h, l);
        Th[(size_t)(n0 + r) * K + k0 + c] = h;
        Tl[(size_t)(n0 + r) * K + k0 + c] = l;
    }
}

// ---------------- split-bf16 MFMA GEMM ----------------
// C = A[M,K] @ B^T[N,K]^T via 3-term split: ahi*bhi + ahi*blo + alo*bhi
// tile 128x128, BK=32, 4 waves (2x2), per-wave 64x64 = 4x4 fragments of 16x16x32.
// LDS rows padded to 40 u16 (80B = 5 chunks, odd mod 8) -> conflict-free ds_read_b128.
// MFMA layouts (guide §3, m89/m91): A row=lane&15, k=(lane>>4)*8+j ; B col=lane&15, same k ;
//                                   C/D col=lane&15, row=(lane>>4)*4+reg.
#define SM_SWISH          0   // split out
#define SM_RESHALF_F32    1   // f32 out = res + 0.5*(acc+bias)
#define SM_RESHALF_SPLIT  2   // split out = res + 0.5*(acc+bias)
#define SM_Q              3   // f32 scatter to [B,H,N,DH]
#define SM_KV             4   // K f32 / V bf16 scatter to [B,H,J,DH]
#define SM_RESBIAS        5   // f32 out = res + acc + bias

template<int MODE>
__global__ __launch_bounds__(256, 2) void mgemm_k(
    const u16* __restrict__ Ahi, const u16* __restrict__ Alo,
    const u16* __restrict__ Bhi, const u16* __restrict__ Blo,
    const float* __restrict__ bias, const float* __restrict__ res,
    float* __restrict__ o1, u16* __restrict__ o2, u16* __restrict__ o3,
    int N, int K, int row0)
{
    __shared__ u16 sAh[128 * 40], sAl[128 * 40], sBh[128 * 40], sBl[128 * 40];

    const int tid  = threadIdx.x;
    const int bm   = blockIdx.y * 128;
    const int bn   = blockIdx.x * 128;
    const int lane = tid & 63;
    const int wid  = tid >> 6;
    const int wr   = (wid >> 1) * 64;
    const int wc   = (wid & 1) * 64;
    const int colL = lane & 15;            // A-row / B-col / C-col within 16
    const int rowL = (lane >> 4) * 4;      // C-row base within 16
    const int kL   = (lane >> 4) * 8;      // fragment k offset

    const f32x4 z4 = {0.f, 0.f, 0.f, 0.f};
    f32x4 acc[4][4];
    #pragma unroll
    for (int i = 0; i < 4; ++i)
        #pragma unroll
        for (int j = 0; j < 4; ++j) acc[i][j] = z4;

    for (int k0 = 0; k0 < K; k0 += 32) {
        __syncthreads();
        #pragma unroll
        for (int q = 0; q < 2; ++q) {
            const int cc = tid + 256 * q;
            const int r  = cc >> 2;             // 0..127
            const int kc = (cc & 3) * 8;        // 0,8,16,24
            const int lo = r * 40 + kc;
            const size_t ga = (size_t)(bm + r) * K + k0 + kc;
            const size_t gb = (size_t)(bn + r) * K + k0 + kc;
            *(uint4*)&sAh[lo] = *(const uint4*)&Ahi[ga];
            *(uint4*)&sAl[lo] = *(const uint4*)&Alo[ga];
            *(uint4*)&sBh[lo] = *(const uint4*)&Bhi[gb];
            *(uint4*)&sBl[lo] = *(const uint4*)&Blo[gb];
        }
        __syncthreads();

        short8 ah[4], al[4], bh[4], bl[4];
        #pragma unroll
        for (int f = 0; f < 4; ++f) {
            const int ra = (wr + f * 16 + colL) * 40 + kL;
            ah[f] = *(const short8*)&sAh[ra];
            al[f] = *(const short8*)&sAl[ra];
            const int rb = (wc + f * 16 + colL) * 40 + kL;
            bh[f] = *(const short8*)&sBh[rb];
            bl[f] = *(const short8*)&sBl[rb];
        }
        #pragma unroll
        for (int fm = 0; fm < 4; ++fm)
            #pragma unroll
            for (int fn = 0; fn < 4; ++fn) {
                acc[fm][fn] = __builtin_amdgcn_mfma_f32_16x16x32_bf16(ah[fm], bh[fn], acc[fm][fn], 0, 0, 0);
                acc[fm][fn] = __builtin_amdgcn_mfma_f32_16x16x32_bf16(ah[fm], bl[fn], acc[fm][fn], 0, 0, 0);
                acc[fm][fn] = __builtin_amdgcn_mfma_f32_16x16x32_bf16(al[fm], bh[fn], acc[fm][fn], 0, 0, 0);
            }
    }

    float biasc[4];
    #pragma unroll
    for (int fn = 0; fn < 4; ++fn) biasc[fn] = bias[bn + wc + fn * 16 + colL];

    #pragma unroll
    for (int fm = 0; fm < 4; ++fm) {
        #pragma unroll
        for (int fn = 0; fn < 4; ++fn) {
            const int gc = bn + wc + fn * 16 + colL;
            #pragma unroll
            for (int r = 0; r < 4; ++r) {
                const int gr = bm + wr + fm * 16 + rowL + r;
                float o = acc[fm][fn][r] + biasc[fn];
                if (MODE == SM_SWISH) {
                    float s = o / (1.f + expf(-o));
                    u16 h, l; split2(s, h, l);
                    o2[(size_t)gr * N + gc] = h;
                    o3[(size_t)gr * N + gc] = l;
                } else if (MODE == SM_RESHALF_F32) {
                    o1[(size_t)gr * N + gc] = res[(size_t)gr * N + gc] + 0.5f * o;
                } else if (MODE == SM_RESHALF_SPLIT) {
                    float v = res[(size_t)gr * N + gc] + 0.5f * o;
                    u16 h, l; split2(v, h, l);
                    o2[(size_t)gr * N + gc] = h;
                    o3[(size_t)gr * N + gc] = l;
                } else if (MODE == SM_Q) {
                    const int b_ = gr >> 6, i_ = gr & 63, h_ = gc >> 7, d_ = gc & 127;
                    o1[(((size_t)(b_ * HEADS + h_) * NN + i_) << 7) + d_] = o;
                } else if (MODE == SM_KV) {
                    const int grow = row0 + gr;
                    const int b_ = grow >> 11, j_ = grow & 2047;
                    if (gc < DIMM) {
                        const int h_ = gc >> 7, d_ = gc & 127;
                        o1[(((size_t)(b_ * HEADS + h_) * JJ + j_) << 7) + d_] = o;
                    } else {
                        const int cc2 = gc - DIMM;
                        const int h_ = cc2 >> 7, d_ = cc2 & 127;
                        o2[(((size_t)(b_ * HEADS + h_) * JJ + j_) << 7) + d_] = bf16rne(o);
                    }
                } else {  // SM_RESBIAS
                    o1[(size_t)gr * N + gc] = res[(size_t)gr * N + gc] + o;
                }
            }
        }
    }
}

// ---------------- dots = scale * Q @ K^T, per (b,h) -- exact f32 (top-k sensitive) ----------------
__global__ __launch_bounds__(256) void dots_k(const float* __restrict__ Q,
                                              const float* __restrict__ Kb,
                                              float* __restrict__ dots)
{
    __shared__ float Qs[32][68];
    __shared__ float Ks[32][132];
    const int bh = blockIdx.y;
    const int jt = blockIdx.x * 128;
    const float* Qp = Q  + (size_t)bh * NN * DH;
    const float* Kp = Kb + (size_t)bh * JJ * DH;
    const int tid = threadIdx.x;
    const int ty = tid >> 4;
    const int tx = tid & 15;

    float acc[4][8];
    #pragma unroll
    for (int i = 0; i < 4; ++i)
        #pragma unroll
        for (int j = 0; j < 8; ++j) acc[i][j] = 0.f;

    for (int d0 = 0; d0 < DH; d0 += 32) {
        __syncthreads();
        #pragma unroll
        for (int q = 0; q < 2; ++q) {
            const int s = tid + 256 * q;
            const int i = s >> 3, dq = s & 7;
            const float4 v = *(const float4*)(Qp + (size_t)i * DH + d0 + dq * 4);
            Qs[dq * 4 + 0][i] = v.x; Qs[dq * 4 + 1][i] = v.y;
            Qs[dq * 4 + 2][i] = v.z; Qs[dq * 4 + 3][i] = v.w;
        }
        #pragma unroll
        for (int q = 0; q < 4; ++q) {
            const int s = tid + 256 * q;
            const int j = s >> 3, dq = s & 7;
            const float4 v = *(const float4*)(Kp + (size_t)(jt + j) * DH + d0 + dq * 4);
            Ks[dq * 4 + 0][j] = v.x; Ks[dq * 4 + 1][j] = v.y;
            Ks[dq * 4 + 2][j] = v.z; Ks[dq * 4 + 3][j] = v.w;
        }
        __syncthreads();
        #pragma unroll
        for (int d = 0; d < 32; ++d) {
            float a[4], b[8];
            *(float4*)&a[0] = *(const float4*)&Qs[d][ty * 4];
            *(float4*)&b[0] = *(const float4*)&Ks[d][tx * 4];
            *(float4*)&b[4] = *(const float4*)&Ks[d][tx * 4 + 64];
            #pragma unroll
            for (int i = 0; i < 4; ++i)
                #pragma unroll
                for (int j = 0; j < 8; ++j)
                    acc[i][j] = fmaf(a[i], b[j], acc[i][j]);
        }
    }

    const float scl = 0.08838834764831845f;
    #pragma unroll
    for (int i = 0; i < 4; ++i) {
        const int row = ty * 4 + i;
        #pragma unroll
        for (int jg = 0; jg < 2; ++jg) {
            const int c = tx * 4 + jg * 64;
            float o[4];
            #pragma unroll
            for (int e = 0; e < 4; ++e) o[e] = acc[i][jg * 4 + e] * scl;
            *(float4*)(dots + ((size_t)bh * NN + row) * JJ + jt + c) = *(float4*)&o[0];
        }
    }
}

// ---------------- exact top-k + masked softmax (unchanged) ----------------
__global__ __launch_bounds__(256) void topk_sm_k(float* __restrict__ dots)
{
    const int wid  = threadIdx.x >> 6;
    const int lane = threadIdx.x & 63;
    const int r = blockIdx.x * 4 + wid;
    const int b = r >> 8;
    const int h = (r >> 6) & 3;
    float* row = dots + (size_t)r * JJ;

    float d[32];
    unsigned key[32];
    #pragma unroll
    for (int t = 0; t < 32; ++t) {
        d[t] = row[lane + 64 * t];
        key[t] = fkey(d[t]);
    }

    unsigned cur = 0u;
    for (int bit = 31; bit >= 0; --bit) {
        const unsigned cand = cur | (1u << bit);
        int c = 0;
        #pragma unroll
        for (int t = 0; t < 32; ++t) c += (key[t] >= cand) ? 1 : 0;
        c = wred_sumi(c);
        if (c >= TOPKK) cur = cand;
    }

    const int LB = (h == 0) ? 1 : (h == 1) ? 4 : (h == 2) ? 8 : 1000;
    float m = -FLTMAXF;
    #pragma unroll
    for (int t = 0; t < 32; ++t) {
        const int j = lane + 64 * t;
        int df = (j >> 6) - b; df = (df < 0) ? -df : df;
        const bool keep = (df <= LB) && (key[t] >= cur);
        d[t] = keep ? d[t] : -FLTMAXF;
        m = fmaxf(m, d[t]);
    }
    m = wred_max(m);

    float s = 0.f;
    float e[32];
    #pragma unroll
    for (int t = 0; t < 32; ++t) {
        e[t] = expf(d[t] - m);
        s += e[t];
    }
    s = wred_sum(s);
    const float inv = 1.0f / s;

    #pragma unroll
    for (int t = 0; t < 32; ++t) row[lane + 64 * t] = e[t] * inv;
}

// ---------------- attn = W @ V (V bf16 in) -> split (hi,lo) out ----------------
__global__ __launch_bounds__(256) void pv_k(const float* __restrict__ Wt,
                                            const u16* __restrict__ Vb,
                                            u16* __restrict__ attnh,
                                            u16* __restrict__ attnl)
{
    __shared__ float Ws[32][36];
    __shared__ float Vs[32][128];
    const int bh = blockIdx.x;
    const int half = blockIdx.y;
    const float* Wp = Wt + (size_t)bh * NN * JJ + (size_t)half * 32 * JJ;
    const u16* Vp = Vb + (size_t)bh * JJ * DH;
    const int tid = threadIdx.x;
    const int ty = tid >> 5;
    const int tx = tid & 31;

    float acc[4][4];
    #pragma unroll
    for (int i = 0; i < 4; ++i)
        #pragma unroll
        for (int j = 0; j < 4; ++j) acc[i][j] = 0.f;

    for (int j0 = 0; j0 < JJ; j0 += 32) {
        __syncthreads();
        {
            const int i = tid >> 3, jq = tid & 7;
            const float4 v = *(const float4*)(Wp + (size_t)i * JJ + j0 + jq * 4);
            Ws[jq * 4 + 0][i] = v.x; Ws[jq * 4 + 1][i] = v.y;
            Ws[jq * 4 + 2][i] = v.z; Ws[jq * 4 + 3][i] = v.w;
        }
        #pragma unroll
        for (int q = 0; q < 2; ++q) {      // V tile 32x128 bf16 -> f32
            const int c = tid + 256 * q;
            const int j = c >> 4, dq = c & 15;
            uint4 v = *(const uint4*)(Vp + (size_t)(j0 + j) * DH + dq * 8);
            const u16* pv = (const u16*)&v;
            #pragma unroll
            for (int e = 0; e < 8; ++e) Vs[j][dq * 8 + e] = bf16tof(pv[e]);
        }
        __syncthreads();
        #pragma unroll
        for (int j = 0; j < 32; ++j) {
            float a[4], bb[4];
            *(float4*)&a[0] = *(const float4*)&Ws[j][ty * 4];
            bb[0] = Vs[j][tx * 2];      bb[1] = Vs[j][tx * 2 + 1];
            bb[2] = Vs[j][tx * 2 + 64]; bb[3] = Vs[j][tx * 2 + 65];
            #pragma unroll
            for (int i = 0; i < 4; ++i)
                #pragma unroll
                for (int jj = 0; jj < 4; ++jj)
                    acc[i][jj] = fmaf(a[i], bb[jj], acc[i][jj]);
        }
    }

    const int b = bh >> 2, h = bh & 3;
    #pragma unroll
    for (int i = 0; i < 4; ++i) {
        const int row = b * NN + half * 32 + ty * 4 + i;
        const size_t base = (size_t)row * DIMM + h * DH;
        u16 h0, l0, h1, l1;
        split2(acc[i][0], h0, l0); split2(acc[i][1], h1, l1);
        *(u32*)(attnh + base + tx * 2) = (u32)h0 | ((u32)h1 << 16);
        *(u32*)(attnl + base + tx * 2) = (u32)l0 | ((u32)l1 << 16);
        split2(acc[i][2], h0, l0); split2(acc[i][3], h1, l1);
        *(u32*)(attnh + base + 64 + tx * 2) = (u32)h0 | ((u32)h1 << 16);
        *(u32*)(attnl + base + 64 + tx * 2) = (u32)l0 | ((u32)l1 << 16);
    }
}

// ---------------- host ----------------
extern "C" void kernel_launch(void* const* d_in, const int* in_sizes, int n_in,
                              void* d_out, int out_size, void* d_ws, size_t ws_size,
                              hipStream_t stream)
{
    if (ws_size < WS_WORDS_REQ * 4ull) return;   // OOB guard (clean fail, not node wedge)

    const float* x       = (const float*)d_in[0];
    const float* ctx     = (const float*)d_in[1];
    const float* ff1_w1  = (const float*)d_in[2];
    const float* ff1_b1  = (const float*)d_in[3];
    const float* ff1_w2  = (const float*)d_in[4];
    const float* ff1_b2  = (const float*)d_in[5];
    const float* ffkv_w1 = (const float*)d_in[6];
    const float* ffkv_b1 = (const float*)d_in[7];
    const float* ffkv_w2 = (const float*)d_in[8];
    const float* ffkv_b2 = (const float*)d_in[9];
    const float* wq      = (const float*)d_in[10];
    const float* bq      = (const float*)d_in[11];
    const float* wkv     = (const float*)d_in[12];
    const float* bkv     = (const float*)d_in[13];
    const float* wo      = (const float*)d_in[14];
    const float* bo      = (const float*)d_in[15];
    const float* ln1_g   = (const float*)d_in[16];
    const float* ln1_b   = (const float*)d_in[17];
    const float* lnkv_g  = (const float*)d_in[18];
    const float* lnkv_b  = (const float*)d_in[19];
    const float* lna_g   = (const float*)d_in[20];
    const float* lna_b   = (const float*)d_in[21];
    const float* lnf_g   = (const float*)d_in[22];
    const float* lnf_b   = (const float*)d_in[23];

    float* ws = (float*)d_ws;
    // word-offset layout (total 74,448,896 words = 297.8 MB):
    float* qb  = ws;                        // 1,048,576 f32  (reused as attn split region later)
    float* Kb  = ws + 1048576;              // 33,554,432 f32
    u16*   Vb  = (u16*)(Kb + 33554432);     // 33,554,432 bf16 (16,777,216 words)
    float* x1  = (float*)Vb + 16777216;     // 1,048,576 f32
    float* wsp = x1 + 1048576;              // 5,242,880 words of weight splits
    float* R   = wsp + 5242880;             // 16,777,216-word union region

    // weight split pointers (u16 units)
    u16* w1Th  = (u16*)wsp;
    u16* w1Tl  = w1Th  + 1048576;
    u16* w2Th  = w1Tl  + 1048576;
    u16* w2Tl  = w2Th  + 1048576;
    u16* kw1Th = w2Tl  + 1048576;
    u16* kw1Tl = kw1Th + 1048576;
    u16* kw2Th = kw1Tl + 1048576;
    u16* kw2Tl = kw2Th + 1048576;
    u16* wqTh  = kw2Tl + 1048576;
    u16* wqTl  = wqTh  + 262144;
    u16* wkvTh = wqTl  + 262144;
    u16* wkvTl = wkvTh + 524288;
    u16* woTh  = wkvTl + 524288;
    u16* woTl  = woTh  + 262144;

    // R overlays -- phase A (x path):
    u16* lnxh  = (u16*)R;
    u16* lnxl  = lnxh  + 1048576;
    u16* hxh   = lnxl  + 1048576;           // [2048][2048]
    u16* hxl   = hxh   + 4194304;
    u16* lnx2h = hxl   + 4194304;
    u16* lnx2l = lnx2h + 1048576;
    // phase B (context chunks):
    u16* lnch  = (u16*)R;                   // [4096][512]
    u16* lncl  = lnch  + 2097152;
    u16* hch   = lncl  + 2097152;           // [4096][2048]
    u16* hcl   = hch   + 8388608;
    u16* ctxnh = hcl   + 8388608;           // [4096][512]
    u16* ctxnl = ctxnh + 2097152;
    // phase C / D:
    float* dots = R;                        // [8192][2048] f32 (exactly 16,777,216)
    float* x2   = R;                        // after dots dead
    u16* attnh  = (u16*)qb;                 // [2048][512] (qb dead after dots_k)
    u16* attnl  = attnh + 1048576;

    // ---- weight transpose+split (runs every call; ~42 MB, trivial) ----
    wsplit_k<<<dim3(FFD / 64, DIMM / 64), 256, 0, stream>>>(ff1_w1,  w1Th,  w1Tl,  DIMM, FFD);
    wsplit_k<<<dim3(DIMM / 64, FFD / 64), 256, 0, stream>>>(ff1_w2,  w2Th,  w2Tl,  FFD,  DIMM);
    wsplit_k<<<dim3(FFD / 64, DIMM / 64), 256, 0, stream>>>(ffkv_w1, kw1Th, kw1Tl, DIMM, FFD);
    wsplit_k<<<dim3(DIMM / 64, FFD / 64), 256, 0, stream>>>(ffkv_w2, kw2Th, kw2Tl, FFD,  DIMM);
    wsplit_k<<<dim3(DIMM / 64, DIMM / 64), 256, 0, stream>>>(wq,     wqTh,  wqTl,  DIMM, DIMM);
    wsplit_k<<<dim3(1024 / 64, DIMM / 64), 256, 0, stream>>>(wkv,    wkvTh, wkvTl, DIMM, 1024);
    wsplit_k<<<dim3(DIMM / 64, DIMM / 64), 256, 0, stream>>>(wo,     woTh,  woTl,  DIMM, DIMM);

    // ---- x path ----
    ln_split_k<<<RX / 4, 256, 0, stream>>>(x, ln1_g, ln1_b, lnxh, lnxl);
    mgemm_k<SM_SWISH><<<dim3(FFD / 128, RX / 128), 256, 0, stream>>>(
        lnxh, lnxl, w1Th, w1Tl, ff1_b1, nullptr, nullptr, hxh, hxl, FFD, DIMM, 0);
    mgemm_k<SM_RESHALF_F32><<<dim3(DIMM / 128, RX / 128), 256, 0, stream>>>(
        hxh, hxl, w2Th, w2Tl, ff1_b2, x, x1, nullptr, nullptr, DIMM, FFD, 0);
    ln_split_k<<<RX / 4, 256, 0, stream>>>(x1, lna_g, lna_b, lnx2h, lnx2l);
    mgemm_k<SM_Q><<<dim3(DIMM / 128, RX / 128), 256, 0, stream>>>(
        lnx2h, lnx2l, wqTh, wqTl, bq, nullptr, qb, nullptr, nullptr, DIMM, DIMM, 0);

    // ---- context chunks ----
    for (int c = 0; c < NCH; ++c) {
        const float* cptr = ctx + (size_t)c * CH * DIMM;
        ln_split_k<<<CH / 4, 256, 0, stream>>>(cptr, lnkv_g, lnkv_b, lnch, lncl);
        mgemm_k<SM_SWISH><<<dim3(FFD / 128, CH / 128), 256, 0, stream>>>(
            lnch, lncl, kw1Th, kw1Tl, ffkv_b1, nullptr, nullptr, hch, hcl, FFD, DIMM, 0);
        mgemm_k<SM_RESHALF_SPLIT><<<dim3(DIMM / 128, CH / 128), 256, 0, stream>>>(
            hch, hcl, kw2Th, kw2Tl, ffkv_b2, cptr, nullptr, ctxnh, ctxnl, DIMM, FFD, 0);
        mgemm_k<SM_KV><<<dim3(1024 / 128, CH / 128), 256, 0, stream>>>(
            ctxnh, ctxnl, wkvTh, wkvTl, bkv, nullptr, Kb, Vb, nullptr, 1024, DIMM, c * CH);
    }

    // ---- attention (exact f32 dots / top-k / softmax) ----
    dots_k<<<dim3(JJ / 128, BB * HEADS), 256, 0, stream>>>(qb, Kb, dots);
    topk_sm_k<<<(BB * HEADS * NN) / 4, 256, 0, stream>>>(dots);
    pv_k<<<dim3(BB * HEADS, 2), 256, 0, stream>>>(dots, Vb, attnh, attnl);

    // ---- output projection + residual + final LN ----
    mgemm_k<SM_RESBIAS><<<dim3(DIMM / 128, RX / 128), 256, 0, stream>>>(
        attnh, attnl, woTh, woTl, bo, x1, x2, nullptr, nullptr, DIMM, DIMM, 0);
    ln_k<<<RX / 4, 256, 0, stream>>>(x2, lnf_g, lnf_b, (float*)d_out);
}

// Round 6
// 2851.533 us; speedup vs baseline: 2.6187x; 1.0331x over previous
//
#include <hip/hip_runtime.h>
#include <math.h>

// ---------------- problem constants ----------------
#define BB     32
#define NN     64
#define DIMM   512
#define HEADS  4
#define DH     128
#define FFD    2048
#define JJ     2048
#define RX     2048
#define TOPKK  64
#define CH     4096
#define NCH    16
#define FLTMAXF 3.402823466e38f

// workspace words (4B) required (297.8 MB; ws >= 356.5 MB proven in R4/R5)
#define WS_WORDS_REQ 74448896ull

typedef unsigned short u16;
typedef unsigned int   u32;

using f32x4  = __attribute__((ext_vector_type(4))) float;
using short8 = __attribute__((ext_vector_type(8))) short;   // 8 bf16 (4 VGPRs)

__device__ __forceinline__ float wred_sum(float v) {
    #pragma unroll
    for (int m = 1; m < 64; m <<= 1) v += __shfl_xor(v, m, 64);
    return v;
}
__device__ __forceinline__ int wred_sumi(int v) {
    #pragma unroll
    for (int m = 1; m < 64; m <<= 1) v += __shfl_xor(v, m, 64);
    return v;
}
__device__ __forceinline__ float wred_max(float v) {
    #pragma unroll
    for (int m = 1; m < 64; m <<= 1) v = fmaxf(v, __shfl_xor(v, m, 64));
    return v;
}
__device__ __forceinline__ unsigned fkey(float f) {
    unsigned u = __float_as_uint(f);
    return (u & 0x80000000u) ? ~u : (u | 0x80000000u);
}

// bf16 helpers (RNE)
__device__ __forceinline__ u16 bf16rne(float f) {
    u32 u = __float_as_uint(f);
    return (u16)((u + 0x7FFFu + ((u >> 16) & 1u)) >> 16);
}
__device__ __forceinline__ float bf16tof(u16 h) {
    return __uint_as_float(((u32)h) << 16);
}
__device__ __forceinline__ void split2(float f, u16& h, u16& l) {
    h = bf16rne(f);
    l = bf16rne(f - bf16tof(h));
}

// async global->LDS, 16B per lane. LDS dest is WAVE-UNIFORM base (+lane*16 by HW),
// global src is per-lane. __syncthreads() drains (compiler emits vmcnt(0) pre-barrier).
__device__ __forceinline__ void gload16(const void* g, void* l) {
    __builtin_amdgcn_global_load_lds(
        (const __attribute__((address_space(1))) void*)g,
        (__attribute__((address_space(3))) void*)l,
        16, 0, 0);
}

// ---------------- LayerNorm (f32 out) ----------------
__global__ __launch_bounds__(256) void ln_k(const float* __restrict__ in,
                                            const float* __restrict__ gam,
                                            const float* __restrict__ bet,
                                            float* __restrict__ out)
{
    const int row  = blockIdx.x * 4 + (threadIdx.x >> 6);
    const int lane = threadIdx.x & 63;
    const float* p = in + (size_t)row * DIMM + lane * 8;

    float a[8];
    *(float4*)&a[0] = *(const float4*)p;
    *(float4*)&a[4] = *(const float4*)(p + 4);

    float s = 0.f;
    #pragma unroll
    for (int i = 0; i < 8; ++i) s += a[i];
    s = wred_sum(s);
    const float mean = s * (1.0f / DIMM);

    float vs = 0.f;
    #pragma unroll
    for (int i = 0; i < 8; ++i) { float d = a[i] - mean; vs += d * d; }
    vs = wred_sum(vs);
    const float var = vs * (1.0f / DIMM) + 1e-5f;
    float r = rsqrtf(var);
    r = r * (1.5f - 0.5f * var * r * r);

    float g[8], b[8];
    *(float4*)&g[0] = *(const float4*)(gam + lane * 8);
    *(float4*)&g[4] = *(const float4*)(gam + lane * 8 + 4);
    *(float4*)&b[0] = *(const float4*)(bet + lane * 8);
    *(float4*)&b[4] = *(const float4*)(bet + lane * 8 + 4);

    float o[8];
    #pragma unroll
    for (int i = 0; i < 8; ++i) o[i] = g[i] * (a[i] - mean) * r + b[i];

    float* q = out + (size_t)row * DIMM + lane * 8;
    *(float4*)q       = *(float4*)&o[0];
    *(float4*)(q + 4) = *(float4*)&o[4];
}

// ---------------- LayerNorm -> split bf16 (hi,lo) ----------------
__global__ __launch_bounds__(256) void ln_split_k(const float* __restrict__ in,
                                                  const float* __restrict__ gam,
                                                  const float* __restrict__ bet,
                                                  u16* __restrict__ oh,
                                                  u16* __restrict__ ol)
{
    const int row  = blockIdx.x * 4 + (threadIdx.x >> 6);
    const int lane = threadIdx.x & 63;
    const float* p = in + (size_t)row * DIMM + lane * 8;

    float a[8];
    *(float4*)&a[0] = *(const float4*)p;
    *(float4*)&a[4] = *(const float4*)(p + 4);

    float s = 0.f;
    #pragma unroll
    for (int i = 0; i < 8; ++i) s += a[i];
    s = wred_sum(s);
    const float mean = s * (1.0f / DIMM);

    float vs = 0.f;
    #pragma unroll
    for (int i = 0; i < 8; ++i) { float d = a[i] - mean; vs += d * d; }
    vs = wred_sum(vs);
    const float var = vs * (1.0f / DIMM) + 1e-5f;
    float r = rsqrtf(var);
    r = r * (1.5f - 0.5f * var * r * r);

    float g[8], b[8];
    *(float4*)&g[0] = *(const float4*)(gam + lane * 8);
    *(float4*)&g[4] = *(const float4*)(gam + lane * 8 + 4);
    *(float4*)&b[0] = *(const float4*)(bet + lane * 8);
    *(float4*)&b[4] = *(const float4*)(bet + lane * 8 + 4);

    u32 ph[4], pl[4];
    #pragma unroll
    for (int i = 0; i < 4; ++i) {
        float o0 = g[2*i]   * (a[2*i]   - mean) * r + b[2*i];
        float o1 = g[2*i+1] * (a[2*i+1] - mean) * r + b[2*i+1];
        u16 h0, l0, h1, l1;
        split2(o0, h0, l0);
        split2(o1, h1, l1);
        ph[i] = (u32)h0 | ((u32)h1 << 16);
        pl[i] = (u32)l0 | ((u32)l1 << 16);
    }
    uint4 vh; vh.x = ph[0]; vh.y = ph[1]; vh.z = ph[2]; vh.w = ph[3];
    uint4 vl; vl.x = pl[0]; vl.y = pl[1]; vl.z = pl[2]; vl.w = pl[3];
    *(uint4*)(oh + (size_t)row * DIMM + lane * 8) = vh;
    *(uint4*)(ol + (size_t)row * DIMM + lane * 8) = vl;
}

// ---------------- weight transpose + split ----------------
__global__ __launch_bounds__(256) void wsplit_k(const float* __restrict__ W,
                                                u16* __restrict__ Th, u16* __restrict__ Tl,
                                                int K, int N)
{
    __shared__ float t[64][65];
    const int k0 = blockIdx.y * 64, n0 = blockIdx.x * 64;
    const int tid = threadIdx.x;
    #pragma unroll
    for (int p = 0; p < 16; ++p) {
        const int idx = p * 256 + tid;
        const int r = idx >> 6, c = idx & 63;
        t[r][c] = W[(size_t)(k0 + r) * N + n0 + c];
    }
    __syncthreads();
    #pragma unroll
    for (int p = 0; p < 16; ++p) {
        const int idx = p * 256 + tid;
        const int r = idx >> 6, c = idx & 63;
        float v = t[c][r];
        u16 h, l; split2(v, h, l);
        Th[(size_t)(n0 + r) * K + k0 + c] = h;
        Tl[(size_t)(n0 + r) * K + k0 + c] = l;
    }
}

// ---------------- split-bf16 MFMA GEMM, global_load_lds staging (m97 structure) ----------------
// C = A[M,K] @ B^T[N,K]^T, 3-term: ahi*bhi + ahi*blo + alo*bhi.
// 128x128 tile, BK=32, 4 waves 2x2, 4x4 frags of 16x16x32.
// LDS LINEAR [128][32] u16 per array (global_load_lds needs contiguous dest);
// 2-phase schedule -> T2 swizzle null (m230/m252), conflicts tolerable (m97: 874 TF with them).
#define SM_SWISH          0
#define SM_RESHALF_F32    1
#define SM_RESHALF_SPLIT  2
#define SM_Q              3   // Q split scatter [b,h,i,d]
#define SM_KV             4   // K split scatter [b,h,j,d]; V bf16 TRANSPOSED [b,h,d,j]
#define SM_RESBIAS        5

template<int MODE>
__global__ __launch_bounds__(256, 2) void mgemm_k(
    const u16* __restrict__ Ahi, const u16* __restrict__ Alo,
    const u16* __restrict__ Bhi, const u16* __restrict__ Blo,
    const float* __restrict__ bias, const float* __restrict__ res,
    float* __restrict__ o1, u16* __restrict__ o2, u16* __restrict__ o3,
    u16* __restrict__ o4, int N, int K, int row0)
{
    __shared__ u16 sAh[128 * 32], sAl[128 * 32], sBh[128 * 32], sBl[128 * 32];

    const int tid  = threadIdx.x;
    const int bm   = blockIdx.y * 128;
    const int bn   = blockIdx.x * 128;
    const int lane = tid & 63;
    const int wid  = tid >> 6;
    const int wr   = (wid >> 1) * 64;
    const int wc   = (wid & 1) * 64;
    const int colL = lane & 15;
    const int rowL = (lane >> 4) * 4;
    const int kL   = (lane >> 4) * 8;
    const int srow = lane >> 2;          // staging: row-in-segment
    const int skc  = (lane & 3) * 8;     // staging: k-chunk (u16)

    const f32x4 z4 = {0.f, 0.f, 0.f, 0.f};
    f32x4 acc[4][4];
    #pragma unroll
    for (int i = 0; i < 4; ++i)
        #pragma unroll
        for (int j = 0; j < 4; ++j) acc[i][j] = z4;

    for (int k0 = 0; k0 < K; k0 += 32) {
        __syncthreads();   // previous-iter reads done before overwrite
        // stage 4 tiles of 128x32 u16; 8 segments/tile; wave w: segs 2w, 2w+1
        #pragma unroll
        for (int ss = 0; ss < 2; ++ss) {
            const int s = wid * 2 + ss;
            const int r = s * 16 + srow;
            const size_t ga = (size_t)(bm + r) * K + k0 + skc;
            const size_t gb = (size_t)(bn + r) * K + k0 + skc;
            gload16(&Ahi[ga], &sAh[s * 512]);
            gload16(&Alo[ga], &sAl[s * 512]);
            gload16(&Bhi[gb], &sBh[s * 512]);
            gload16(&Blo[gb], &sBl[s * 512]);
        }
        __syncthreads();   // vmcnt(0) drain + barrier

        short8 ah[4], al[4], bh[4], bl[4];
        #pragma unroll
        for (int f = 0; f < 4; ++f) {
            const int ra = (wr + f * 16 + colL) * 32 + kL;
            ah[f] = *(const short8*)&sAh[ra];
            al[f] = *(const short8*)&sAl[ra];
            const int rb = (wc + f * 16 + colL) * 32 + kL;
            bh[f] = *(const short8*)&sBh[rb];
            bl[f] = *(const short8*)&sBl[rb];
        }
        #pragma unroll
        for (int fm = 0; fm < 4; ++fm)
            #pragma unroll
            for (int fn = 0; fn < 4; ++fn) {
                acc[fm][fn] = __builtin_amdgcn_mfma_f32_16x16x32_bf16(ah[fm], bh[fn], acc[fm][fn], 0, 0, 0);
                acc[fm][fn] = __builtin_amdgcn_mfma_f32_16x16x32_bf16(ah[fm], bl[fn], acc[fm][fn], 0, 0, 0);
                acc[fm][fn] = __builtin_amdgcn_mfma_f32_16x16x32_bf16(al[fm], bh[fn], acc[fm][fn], 0, 0, 0);
            }
    }

    float biasc[4];
    #pragma unroll
    for (int fn = 0; fn < 4; ++fn) biasc[fn] = bias[bn + wc + fn * 16 + colL];

    #pragma unroll
    for (int fm = 0; fm < 4; ++fm) {
        #pragma unroll
        for (int fn = 0; fn < 4; ++fn) {
            const int gc = bn + wc + fn * 16 + colL;
            #pragma unroll
            for (int r = 0; r < 4; ++r) {
                const int gr = bm + wr + fm * 16 + rowL + r;
                float o = acc[fm][fn][r] + biasc[fn];
                if (MODE == SM_SWISH) {
                    float s = o / (1.f + expf(-o));
                    u16 h, l; split2(s, h, l);
                    o2[(size_t)gr * N + gc] = h;
                    o3[(size_t)gr * N + gc] = l;
                } else if (MODE == SM_RESHALF_F32) {
                    o1[(size_t)gr * N + gc] = res[(size_t)gr * N + gc] + 0.5f * o;
                } else if (MODE == SM_RESHALF_SPLIT) {
                    float v = res[(size_t)gr * N + gc] + 0.5f * o;
                    u16 h, l; split2(v, h, l);
                    o2[(size_t)gr * N + gc] = h;
                    o3[(size_t)gr * N + gc] = l;
                } else if (MODE == SM_Q) {
                    const int b_ = gr >> 6, i_ = gr & 63, h_ = gc >> 7, d_ = gc & 127;
                    const size_t idx = (((size_t)(b_ * HEADS + h_) * NN + i_) << 7) + d_;
                    u16 h, l; split2(o, h, l);
                    o2[idx] = h; o3[idx] = l;
                } else if (MODE == SM_KV) {
                    const int grow = row0 + gr;
                    const int b_ = grow >> 11, j_ = grow & 2047;
                    if (gc < DIMM) {
                        const int h_ = gc >> 7, d_ = gc & 127;
                        const size_t idx = (((size_t)(b_ * HEADS + h_) * JJ + j_) << 7) + d_;
                        u16 h, l; split2(o, h, l);
                        o2[idx] = h; o3[idx] = l;
                    } else {
                        const int cc2 = gc - DIMM;
                        const int h_ = cc2 >> 7, d_ = cc2 & 127;
                        o4[((size_t)(b_ * HEADS + h_) * DH + d_) * JJ + j_] = bf16rne(o);
                    }
                } else {  // SM_RESBIAS
                    o1[(size_t)gr * N + gc] = res[(size_t)gr * N + gc] + o;
                }
            }
        }
    }
}

// ---------------- dots = scale * Q @ K^T (3-term split MFMA) ----------------
// grid (J/128, B*H); block 256 = 4 waves 2x2: wave = 32 q-rows x 64 j-cols.
__global__ __launch_bounds__(256, 2) void dmfma_k(
    const u16* __restrict__ Qh, const u16* __restrict__ Ql,
    const u16* __restrict__ Kh, const u16* __restrict__ Kl,
    float* __restrict__ dots)
{
    __shared__ u16 sQh[64 * 32], sQl[64 * 32], sKh[128 * 32], sKl[128 * 32];

    const int tid  = threadIdx.x;
    const int bh   = blockIdx.y;
    const int jt   = blockIdx.x * 128;
    const int lane = tid & 63;
    const int wid  = tid >> 6;
    const int wr   = (wid >> 1) * 32;
    const int wc   = (wid & 1) * 64;
    const int colL = lane & 15;
    const int rowL = (lane >> 4) * 4;
    const int kL   = (lane >> 4) * 8;
    const int srow = lane >> 2;
    const int skc  = (lane & 3) * 8;

    const size_t qbase = (size_t)bh * NN * DH;
    const size_t kbase = (size_t)bh * JJ * DH;

    const f32x4 z4 = {0.f, 0.f, 0.f, 0.f};
    f32x4 acc[2][4];
    #pragma unroll
    for (int i = 0; i < 2; ++i)
        #pragma unroll
        for (int j = 0; j < 4; ++j) acc[i][j] = z4;

    for (int d0 = 0; d0 < DH; d0 += 32) {
        __syncthreads();
        {   // Q tile 64x32: 4 segs; wave w -> seg w
            const size_t gq = qbase + (size_t)(wid * 16 + srow) * DH + d0 + skc;
            gload16(&Qh[gq], &sQh[wid * 512]);
            gload16(&Ql[gq], &sQl[wid * 512]);
        }
        #pragma unroll
        for (int ss = 0; ss < 2; ++ss) {   // K tile 128x32: 8 segs; wave w -> 2w, 2w+1
            const int s = wid * 2 + ss;
            const size_t gk = kbase + (size_t)(jt + s * 16 + srow) * DH + d0 + skc;
            gload16(&Kh[gk], &sKh[s * 512]);
            gload16(&Kl[gk], &sKl[s * 512]);
        }
        __syncthreads();

        short8 qh[2], ql[2], kh[4], kl[4];
        #pragma unroll
        for (int f = 0; f < 2; ++f) {
            const int ra = (wr + f * 16 + colL) * 32 + kL;
            qh[f] = *(const short8*)&sQh[ra];
            ql[f] = *(const short8*)&sQl[ra];
        }
        #pragma unroll
        for (int f = 0; f < 4; ++f) {
            const int rb = (wc + f * 16 + colL) * 32 + kL;
            kh[f] = *(const short8*)&sKh[rb];
            kl[f] = *(const short8*)&sKl[rb];
        }
        #pragma unroll
        for (int fm = 0; fm < 2; ++fm)
            #pragma unroll
            for (int fn = 0; fn < 4; ++fn) {
                acc[fm][fn] = __builtin_amdgcn_mfma_f32_16x16x32_bf16(qh[fm], kh[fn], acc[fm][fn], 0, 0, 0);
                acc[fm][fn] = __builtin_amdgcn_mfma_f32_16x16x32_bf16(qh[fm], kl[fn], acc[fm][fn], 0, 0, 0);
                acc[fm][fn] = __builtin_amdgcn_mfma_f32_16x16x32_bf16(ql[fm], kh[fn], acc[fm][fn], 0, 0, 0);
            }
    }

    const float scl = 0.08838834764831845f;
    #pragma unroll
    for (int fm = 0; fm < 2; ++fm)
        #pragma unroll
        for (int fn = 0; fn < 4; ++fn)
            #pragma unroll
            for (int r = 0; r < 4; ++r) {
                const int qi = wr + fm * 16 + rowL + r;
                const int jc = jt + wc + fn * 16 + colL;
                dots[((size_t)bh * NN + qi) * JJ + jc] = acc[fm][fn][r] * scl;
            }
}

// ---------------- top-k + masked softmax; emits P as bf16 IN-PLACE ----------------
// one wave per row (all loads into regs before any store -> in-place safe).
// P row r lives in the first 4096 B of the f32 dots row (u16 pitch 2*JJ).
__global__ __launch_bounds__(256) void topk_sm_k(float* __restrict__ dots)
{
    const int wid  = threadIdx.x >> 6;
    const int lane = threadIdx.x & 63;
    const int r = blockIdx.x * 4 + wid;
    const int b = r >> 8;
    const int h = (r >> 6) & 3;
    float* row = dots + (size_t)r * JJ;

    float d[32];
    unsigned key[32];
    #pragma unroll
    for (int t = 0; t < 32; ++t) {
        d[t] = row[lane + 64 * t];
        key[t] = fkey(d[t]);
    }

    unsigned cur = 0u;
    for (int bit = 31; bit >= 0; --bit) {
        const unsigned cand = cur | (1u << bit);
        int c = 0;
        #pragma unroll
        for (int t = 0; t < 32; ++t) c += (key[t] >= cand) ? 1 : 0;
        c = wred_sumi(c);
        if (c >= TOPKK) cur = cand;
    }

    const int LB = (h == 0) ? 1 : (h == 1) ? 4 : (h == 2) ? 8 : 1000;
    float m = -FLTMAXF;
    #pragma unroll
    for (int t = 0; t < 32; ++t) {
        const int j = lane + 64 * t;
        int df = (j >> 6) - b; df = (df < 0) ? -df : df;
        const bool keep = (df <= LB) && (key[t] >= cur);
        d[t] = keep ? d[t] : -FLTMAXF;
        m = fmaxf(m, d[t]);
    }
    m = wred_max(m);

    float s = 0.f;
    float e[32];
    #pragma unroll
    for (int t = 0; t < 32; ++t) {
        e[t] = expf(d[t] - m);
        s += e[t];
    }
    s = wred_sum(s);
    const float inv = 1.0f / s;

    u16* prow = (u16*)row;
    #pragma unroll
    for (int t = 0; t < 32; ++t) prow[lane + 64 * t] = bf16rne(e[t] * inv);
}

// ---------------- attn = P @ V^T-layout (bf16 MFMA, 1-term) ----------------
// grid (B*H); block 256 = 4 waves 2x2: wave = 32 q-rows x 64 d-cols; K-loop j=2048.
__global__ __launch_bounds__(256, 2) void pvm_k(
    const u16* __restrict__ Pb,     // [bh][i][j], row pitch 2*JJ u16 (in dots buffer)
    const u16* __restrict__ Vt,     // [bh][d][j]
    u16* __restrict__ attnh, u16* __restrict__ attnl)
{
    __shared__ u16 sP[64 * 32], sVt[128 * 32];

    const int tid  = threadIdx.x;
    const int bh   = blockIdx.x;
    const int lane = tid & 63;
    const int wid  = tid >> 6;
    const int wr   = (wid >> 1) * 32;
    const int wc   = (wid & 1) * 64;
    const int colL = lane & 15;
    const int rowL = (lane >> 4) * 4;
    const int kL   = (lane >> 4) * 8;
    const int srow = lane >> 2;
    const int skc  = (lane & 3) * 8;

    const size_t pbase = (size_t)bh * NN * (2 * JJ);
    const size_t vbase = (size_t)bh * DH * JJ;

    const f32x4 z4 = {0.f, 0.f, 0.f, 0.f};
    f32x4 acc[2][4];
    #pragma unroll
    for (int i = 0; i < 2; ++i)
        #pragma unroll
        for (int j = 0; j < 4; ++j) acc[i][j] = z4;

    for (int j0 = 0; j0 < JJ; j0 += 32) {
        __syncthreads();
        {   // P tile 64x32: wave w -> seg w
            const size_t gp = pbase + (size_t)(wid * 16 + srow) * (2 * JJ) + j0 + skc;
            gload16(&Pb[gp], &sP[wid * 512]);
        }
        #pragma unroll
        for (int ss = 0; ss < 2; ++ss) {   // Vt tile 128x32: wave w -> segs 2w, 2w+1
            const int s = wid * 2 + ss;
            const size_t gv = vbase + (size_t)(s * 16 + srow) * JJ + j0 + skc;
            gload16(&Vt[gv], &sVt[s * 512]);
        }
        __syncthreads();

        short8 pf[2], vf[4];
        #pragma unroll
        for (int f = 0; f < 2; ++f)
            pf[f] = *(const short8*)&sP[(wr + f * 16 + colL) * 32 + kL];
        #pragma unroll
        for (int f = 0; f < 4; ++f)
            vf[f] = *(const short8*)&sVt[(wc + f * 16 + colL) * 32 + kL];
        #pragma unroll
        for (int fm = 0; fm < 2; ++fm)
            #pragma unroll
            for (int fn = 0; fn < 4; ++fn)
                acc[fm][fn] = __builtin_amdgcn_mfma_f32_16x16x32_bf16(pf[fm], vf[fn], acc[fm][fn], 0, 0, 0);
    }

    const int b = bh >> 2, h = bh & 3;
    #pragma unroll
    for (int fm = 0; fm < 2; ++fm)
        #pragma unroll
        for (int fn = 0; fn < 4; ++fn)
            #pragma unroll
            for (int r = 0; r < 4; ++r) {
                const int i = wr + fm * 16 + rowL + r;
                const int dcol = wc + fn * 16 + colL;
                const size_t idx = (size_t)(b * NN + i) * DIMM + h * DH + dcol;
                u16 hh, ll; split2(acc[fm][fn][r], hh, ll);
                attnh[idx] = hh; attnl[idx] = ll;
            }
}

// ---------------- host ----------------
extern "C" void kernel_launch(void* const* d_in, const int* in_sizes, int n_in,
                              void* d_out, int out_size, void* d_ws, size_t ws_size,
                              hipStream_t stream)
{
    if (ws_size < WS_WORDS_REQ * 4ull) return;   // OOB guard

    const float* x       = (const float*)d_in[0];
    const float* ctx     = (const float*)d_in[1];
    const float* ff1_w1  = (const float*)d_in[2];
    const float* ff1_b1  = (const float*)d_in[3];
    const float* ff1_w2  = (const float*)d_in[4];
    const float* ff1_b2  = (const float*)d_in[5];
    const float* ffkv_w1 = (const float*)d_in[6];
    const float* ffkv_b1 = (const float*)d_in[7];
    const float* ffkv_w2 = (const float*)d_in[8];
    const float* ffkv_b2 = (const float*)d_in[9];
    const float* wq      = (const float*)d_in[10];
    const float* bq      = (const float*)d_in[11];
    const float* wkv     = (const float*)d_in[12];
    const float* bkv     = (const float*)d_in[13];
    const float* wo      = (const float*)d_in[14];
    const float* bo      = (const float*)d_in[15];
    const float* ln1_g   = (const float*)d_in[16];
    const float* ln1_b   = (const float*)d_in[17];
    const float* lnkv_g  = (const float*)d_in[18];
    const float* lnkv_b  = (const float*)d_in[19];
    const float* lna_g   = (const float*)d_in[20];
    const float* lna_b   = (const float*)d_in[21];
    const float* lnf_g   = (const float*)d_in[22];
    const float* lnf_b   = (const float*)d_in[23];

    float* ws = (float*)d_ws;
    // word layout (74,448,896 words = 297.8 MB):
    // [0 .. 1M)      : Q split (Qh,Ql) -> reused for attn split after dots
    // [1M .. 34.5M)  : K split (Khi, Klo)  [each 16,777,216 words-worth of u16]
    // [34.5M .. 51.3M): Vt bf16 [bh][d][j]
    // [51.3M .. 52.3M): x1 f32
    // [52.3M .. 57.6M): weight splits
    // [57.6M .. 74.4M): union R (dots f32 / P bf16 in-place / x2)
    u16*   Qhs = (u16*)ws;                      // 1,048,576 u16
    u16*   Qls = Qhs + 1048576;                 // 1,048,576 u16
    u16*   Khs = (u16*)(ws + 1048576);          // 33,554,432 u16
    u16*   Kls = Khs + 33554432;                // 33,554,432 u16
    u16*   Vt  = (u16*)(ws + 34603008);         // 33,554,432 u16
    float* x1  = ws + 51380224;                 // 1,048,576 f32
    float* wsp = x1 + 1048576;                  // 5,242,880 words
    float* R   = wsp + 5242880;                 // 16,777,216 words

    u16* w1Th  = (u16*)wsp;
    u16* w1Tl  = w1Th  + 1048576;
    u16* w2Th  = w1Tl  + 1048576;
    u16* w2Tl  = w2Th  + 1048576;
    u16* kw1Th = w2Tl  + 1048576;
    u16* kw1Tl = kw1Th + 1048576;
    u16* kw2Th = kw1Tl + 1048576;
    u16* kw2Tl = kw2Th + 1048576;
    u16* wqTh  = kw2Tl + 1048576;
    u16* wqTl  = wqTh  + 262144;
    u16* wkvTh = wqTl  + 262144;
    u16* wkvTl = wkvTh + 524288;
    u16* woTh  = wkvTl + 524288;
    u16* woTl  = woTh  + 262144;

    // R overlays (temporally disjoint):
    u16* lnxh  = (u16*)R;                       // x path
    u16* lnxl  = lnxh  + 1048576;
    u16* hxh   = lnxl  + 1048576;
    u16* hxl   = hxh   + 4194304;
    u16* lnx2h = hxl   + 4194304;
    u16* lnx2l = lnx2h + 1048576;
    u16* lnch  = (u16*)R;                       // context chunks
    u16* lncl  = lnch  + 2097152;
    u16* hch   = lncl  + 2097152;
    u16* hcl   = hch   + 8388608;
    u16* ctxnh = hcl   + 8388608;
    u16* ctxnl = ctxnh + 2097152;
    float* dots = R;                            // [8192][2048] f32; P bf16 in-place
    float* x2   = R;                            // after P dead
    u16* attnh  = (u16*)ws;                     // over dead Q split
    u16* attnl  = attnh + 1048576;

    // ---- weight transpose+split ----
    wsplit_k<<<dim3(FFD / 64, DIMM / 64), 256, 0, stream>>>(ff1_w1,  w1Th,  w1Tl,  DIMM, FFD);
    wsplit_k<<<dim3(DIMM / 64, FFD / 64), 256, 0, stream>>>(ff1_w2,  w2Th,  w2Tl,  FFD,  DIMM);
    wsplit_k<<<dim3(FFD / 64, DIMM / 64), 256, 0, stream>>>(ffkv_w1, kw1Th, kw1Tl, DIMM, FFD);
    wsplit_k<<<dim3(DIMM / 64, FFD / 64), 256, 0, stream>>>(ffkv_w2, kw2Th, kw2Tl, FFD,  DIMM);
    wsplit_k<<<dim3(DIMM / 64, DIMM / 64), 256, 0, stream>>>(wq,     wqTh,  wqTl,  DIMM, DIMM);
    wsplit_k<<<dim3(1024 / 64, DIMM / 64), 256, 0, stream>>>(wkv,    wkvTh, wkvTl, DIMM, 1024);
    wsplit_k<<<dim3(DIMM / 64, DIMM / 64), 256, 0, stream>>>(wo,     woTh,  woTl,  DIMM, DIMM);

    // ---- x path ----
    ln_split_k<<<RX / 4, 256, 0, stream>>>(x, ln1_g, ln1_b, lnxh, lnxl);
    mgemm_k<SM_SWISH><<<dim3(FFD / 128, RX / 128), 256, 0, stream>>>(
        lnxh, lnxl, w1Th, w1Tl, ff1_b1, nullptr, nullptr, hxh, hxl, nullptr, FFD, DIMM, 0);
    mgemm_k<SM_RESHALF_F32><<<dim3(DIMM / 128, RX / 128), 256, 0, stream>>>(
        hxh, hxl, w2Th, w2Tl, ff1_b2, x, x1, nullptr, nullptr, nullptr, DIMM, FFD, 0);
    ln_split_k<<<RX / 4, 256, 0, stream>>>(x1, lna_g, lna_b, lnx2h, lnx2l);
    mgemm_k<SM_Q><<<dim3(DIMM / 128, RX / 128), 256, 0, stream>>>(
        lnx2h, lnx2l, wqTh, wqTl, bq, nullptr, nullptr, Qhs, Qls, nullptr, DIMM, DIMM, 0);

    // ---- context chunks ----
    for (int c = 0; c < NCH; ++c) {
        const float* cptr = ctx + (size_t)c * CH * DIMM;
        ln_split_k<<<CH / 4, 256, 0, stream>>>(cptr, lnkv_g, lnkv_b, lnch, lncl);
        mgemm_k<SM_SWISH><<<dim3(FFD / 128, CH / 128), 256, 0, stream>>>(
            lnch, lncl, kw1Th, kw1Tl, ffkv_b1, nullptr, nullptr, hch, hcl, nullptr, FFD, DIMM, 0);
        mgemm_k<SM_RESHALF_SPLIT><<<dim3(DIMM / 128, CH / 128), 256, 0, stream>>>(
            hch, hcl, kw2Th, kw2Tl, ffkv_b2, cptr, nullptr, ctxnh, ctxnl, nullptr, DIMM, FFD, 0);
        mgemm_k<SM_KV><<<dim3(1024 / 128, CH / 128), 256, 0, stream>>>(
            ctxnh, ctxnl, wkvTh, wkvTl, bkv, nullptr, nullptr, Khs, Kls, Vt, 1024, DIMM, c * CH);
    }

    // ---- attention ----
    dmfma_k<<<dim3(JJ / 128, BB * HEADS), 256, 0, stream>>>(Qhs, Qls, Khs, Kls, dots);
    topk_sm_k<<<(BB * HEADS * NN) / 4, 256, 0, stream>>>(dots);
    pvm_k<<<BB * HEADS, 256, 0, stream>>>((const u16*)dots, Vt, attnh, attnl);

    // ---- output projection + residual + final LN ----
    mgemm_k<SM_RESBIAS><<<dim3(DIMM / 128, RX / 128), 256, 0, stream>>>(
        attnh, attnl, woTh, woTl, bo, x1, x2, nullptr, nullptr, nullptr, DIMM, DIMM, 0);
    ln_k<<<RX / 4, 256, 0, stream>>>(x2, lnf_g, lnf_b, (float*)d_out);
}

// Round 7
// 2088.882 us; speedup vs baseline: 3.5748x; 1.3651x over previous
//
#include <hip/hip_runtime.h>
#include <math.h>

// ---------------- problem constants ----------------
#define BB     32
#define NN     64
#define DIMM   512
#define HEADS  4
#define DH     128
#define FFD    2048
#define JJ     2048
#define RX     2048
#define TOPKK  64
#define CH     8192          // context chunk rows (R6: 4096 -> 8192, grids 2x)
#define NCH    8
#define FLTMAXF 3.402823466e38f

// workspace words (4B) required (331.4 MB; ws >= 356.5 MB proven in R4/R5)
#define WS_WORDS_REQ 82837504ull

typedef unsigned short u16;
typedef unsigned int   u32;

using f32x4  = __attribute__((ext_vector_type(4))) float;
using short8 = __attribute__((ext_vector_type(8))) short;   // 8 bf16 (4 VGPRs)

__device__ __forceinline__ float wred_sum(float v) {
    #pragma unroll
    for (int m = 1; m < 64; m <<= 1) v += __shfl_xor(v, m, 64);
    return v;
}
__device__ __forceinline__ int wred_sumi(int v) {
    #pragma unroll
    for (int m = 1; m < 64; m <<= 1) v += __shfl_xor(v, m, 64);
    return v;
}
__device__ __forceinline__ float wred_max(float v) {
    #pragma unroll
    for (int m = 1; m < 64; m <<= 1) v = fmaxf(v, __shfl_xor(v, m, 64));
    return v;
}
__device__ __forceinline__ unsigned fkey(float f) {
    unsigned u = __float_as_uint(f);
    return (u & 0x80000000u) ? ~u : (u | 0x80000000u);
}

// bf16 helpers (RNE)
__device__ __forceinline__ u16 bf16rne(float f) {
    u32 u = __float_as_uint(f);
    return (u16)((u + 0x7FFFu + ((u >> 16) & 1u)) >> 16);
}
__device__ __forceinline__ float bf16tof(u16 h) {
    return __uint_as_float(((u32)h) << 16);
}
__device__ __forceinline__ void split2(float f, u16& h, u16& l) {
    h = bf16rne(f);
    l = bf16rne(f - bf16tof(h));
}

// async global->LDS, 16B/lane; LDS dest wave-uniform base, global src per-lane.
__device__ __forceinline__ void gload16(const void* g, void* l) {
    __builtin_amdgcn_global_load_lds(
        (const __attribute__((address_space(1))) void*)g,
        (__attribute__((address_space(3))) void*)l,
        16, 0, 0);
}

// ---------------- LayerNorm (f32 out) ----------------
__global__ __launch_bounds__(256) void ln_k(const float* __restrict__ in,
                                            const float* __restrict__ gam,
                                            const float* __restrict__ bet,
                                            float* __restrict__ out)
{
    const int row  = blockIdx.x * 4 + (threadIdx.x >> 6);
    const int lane = threadIdx.x & 63;
    const float* p = in + (size_t)row * DIMM + lane * 8;

    float a[8];
    *(float4*)&a[0] = *(const float4*)p;
    *(float4*)&a[4] = *(const float4*)(p + 4);

    float s = 0.f;
    #pragma unroll
    for (int i = 0; i < 8; ++i) s += a[i];
    s = wred_sum(s);
    const float mean = s * (1.0f / DIMM);

    float vs = 0.f;
    #pragma unroll
    for (int i = 0; i < 8; ++i) { float d = a[i] - mean; vs += d * d; }
    vs = wred_sum(vs);
    const float var = vs * (1.0f / DIMM) + 1e-5f;
    float r = rsqrtf(var);
    r = r * (1.5f - 0.5f * var * r * r);

    float g[8], b[8];
    *(float4*)&g[0] = *(const float4*)(gam + lane * 8);
    *(float4*)&g[4] = *(const float4*)(gam + lane * 8 + 4);
    *(float4*)&b[0] = *(const float4*)(bet + lane * 8);
    *(float4*)&b[4] = *(const float4*)(bet + lane * 8 + 4);

    float o[8];
    #pragma unroll
    for (int i = 0; i < 8; ++i) o[i] = g[i] * (a[i] - mean) * r + b[i];

    float* q = out + (size_t)row * DIMM + lane * 8;
    *(float4*)q       = *(float4*)&o[0];
    *(float4*)(q + 4) = *(float4*)&o[4];
}

// ---------------- LayerNorm -> split bf16 (hi,lo) ----------------
__global__ __launch_bounds__(256) void ln_split_k(const float* __restrict__ in,
                                                  const float* __restrict__ gam,
                                                  const float* __restrict__ bet,
                                                  u16* __restrict__ oh,
                                                  u16* __restrict__ ol)
{
    const int row  = blockIdx.x * 4 + (threadIdx.x >> 6);
    const int lane = threadIdx.x & 63;
    const float* p = in + (size_t)row * DIMM + lane * 8;

    float a[8];
    *(float4*)&a[0] = *(const float4*)p;
    *(float4*)&a[4] = *(const float4*)(p + 4);

    float s = 0.f;
    #pragma unroll
    for (int i = 0; i < 8; ++i) s += a[i];
    s = wred_sum(s);
    const float mean = s * (1.0f / DIMM);

    float vs = 0.f;
    #pragma unroll
    for (int i = 0; i < 8; ++i) { float d = a[i] - mean; vs += d * d; }
    vs = wred_sum(vs);
    const float var = vs * (1.0f / DIMM) + 1e-5f;
    float r = rsqrtf(var);
    r = r * (1.5f - 0.5f * var * r * r);

    float g[8], b[8];
    *(float4*)&g[0] = *(const float4*)(gam + lane * 8);
    *(float4*)&g[4] = *(const float4*)(gam + lane * 8 + 4);
    *(float4*)&b[0] = *(const float4*)(bet + lane * 8);
    *(float4*)&b[4] = *(const float4*)(bet + lane * 8 + 4);

    u32 ph[4], pl[4];
    #pragma unroll
    for (int i = 0; i < 4; ++i) {
        float o0 = g[2*i]   * (a[2*i]   - mean) * r + b[2*i];
        float o1 = g[2*i+1] * (a[2*i+1] - mean) * r + b[2*i+1];
        u16 h0, l0, h1, l1;
        split2(o0, h0, l0);
        split2(o1, h1, l1);
        ph[i] = (u32)h0 | ((u32)h1 << 16);
        pl[i] = (u32)l0 | ((u32)l1 << 16);
    }
    uint4 vh; vh.x = ph[0]; vh.y = ph[1]; vh.z = ph[2]; vh.w = ph[3];
    uint4 vl; vl.x = pl[0]; vl.y = pl[1]; vl.z = pl[2]; vl.w = pl[3];
    *(uint4*)(oh + (size_t)row * DIMM + lane * 8) = vh;
    *(uint4*)(ol + (size_t)row * DIMM + lane * 8) = vl;
}

// ---------------- weight transpose + split ----------------
__global__ __launch_bounds__(256) void wsplit_k(const float* __restrict__ W,
                                                u16* __restrict__ Th, u16* __restrict__ Tl,
                                                int K, int N)
{
    __shared__ float t[64][65];
    const int k0 = blockIdx.y * 64, n0 = blockIdx.x * 64;
    const int tid = threadIdx.x;
    #pragma unroll
    for (int p = 0; p < 16; ++p) {
        const int idx = p * 256 + tid;
        const int r = idx >> 6, c = idx & 63;
        t[r][c] = W[(size_t)(k0 + r) * N + n0 + c];
    }
    __syncthreads();
    #pragma unroll
    for (int p = 0; p < 16; ++p) {
        const int idx = p * 256 + tid;
        const int r = idx >> 6, c = idx & 63;
        float v = t[c][r];
        u16 h, l; split2(v, h, l);
        Th[(size_t)(n0 + r) * K + k0 + c] = h;
        Tl[(size_t)(n0 + r) * K + k0 + c] = l;
    }
}

// ---------------- split-bf16 MFMA GEMM, global_load_lds staging + XCD swizzle ----------------
// C = A[M,K] @ B^T[N,K]^T, 3-term: ahi*bhi + ahi*blo + alo*bhi.
// 128x128 tile, BK=32, 4 waves 2x2, 4x4 frags of 16x16x32.
// XCD swizzle (T1, m157/m192): hardware round-robins flat bid across 8 XCDs; remap so each
// XCD owns a CONTIGUOUS tile range -> A row-panels stay XCD-local in L2 (R6 FETCH showed
// ~8x A duplication: 73.8 MB vs ~12.6 ideal). Requires nwg % 8 == 0 (all launches comply).
#define SM_SWISH          0
#define SM_RESHALF_F32    1
#define SM_RESHALF_SPLIT  2
#define SM_Q              3
#define SM_KV             4
#define SM_RESBIAS        5

template<int MODE>
__global__ __launch_bounds__(256, 2) void mgemm_k(
    const u16* __restrict__ Ahi, const u16* __restrict__ Alo,
    const u16* __restrict__ Bhi, const u16* __restrict__ Blo,
    const float* __restrict__ bias, const float* __restrict__ res,
    float* __restrict__ o1, u16* __restrict__ o2, u16* __restrict__ o3,
    u16* __restrict__ o4, int N, int K, int row0)
{
    __shared__ u16 sAh[128 * 32], sAl[128 * 32], sBh[128 * 32], sBl[128 * 32];

    const int tid  = threadIdx.x;
    // bijective XCD-chunk swizzle (nwg multiple of 8)
    const int nwg  = gridDim.x * gridDim.y;
    int bid = blockIdx.y * gridDim.x + blockIdx.x;
    bid = (bid & 7) * (nwg >> 3) + (bid >> 3);
    const int bm   = (bid / gridDim.x) * 128;
    const int bn   = (bid % gridDim.x) * 128;

    const int lane = tid & 63;
    const int wid  = tid >> 6;
    const int wr   = (wid >> 1) * 64;
    const int wc   = (wid & 1) * 64;
    const int colL = lane & 15;
    const int rowL = (lane >> 4) * 4;
    const int kL   = (lane >> 4) * 8;
    const int srow = lane >> 2;
    const int skc  = (lane & 3) * 8;

    const f32x4 z4 = {0.f, 0.f, 0.f, 0.f};
    f32x4 acc[4][4];
    #pragma unroll
    for (int i = 0; i < 4; ++i)
        #pragma unroll
        for (int j = 0; j < 4; ++j) acc[i][j] = z4;

    for (int k0 = 0; k0 < K; k0 += 32) {
        __syncthreads();
        #pragma unroll
        for (int ss = 0; ss < 2; ++ss) {
            const int s = wid * 2 + ss;
            const int r = s * 16 + srow;
            const size_t ga = (size_t)(bm + r) * K + k0 + skc;
            const size_t gb = (size_t)(bn + r) * K + k0 + skc;
            gload16(&Ahi[ga], &sAh[s * 512]);
            gload16(&Alo[ga], &sAl[s * 512]);
            gload16(&Bhi[gb], &sBh[s * 512]);
            gload16(&Blo[gb], &sBl[s * 512]);
        }
        __syncthreads();

        short8 ah[4], al[4], bh[4], bl[4];
        #pragma unroll
        for (int f = 0; f < 4; ++f) {
            const int ra = (wr + f * 16 + colL) * 32 + kL;
            ah[f] = *(const short8*)&sAh[ra];
            al[f] = *(const short8*)&sAl[ra];
            const int rb = (wc + f * 16 + colL) * 32 + kL;
            bh[f] = *(const short8*)&sBh[rb];
            bl[f] = *(const short8*)&sBl[rb];
        }
        #pragma unroll
        for (int fm = 0; fm < 4; ++fm)
            #pragma unroll
            for (int fn = 0; fn < 4; ++fn) {
                acc[fm][fn] = __builtin_amdgcn_mfma_f32_16x16x32_bf16(ah[fm], bh[fn], acc[fm][fn], 0, 0, 0);
                acc[fm][fn] = __builtin_amdgcn_mfma_f32_16x16x32_bf16(ah[fm], bl[fn], acc[fm][fn], 0, 0, 0);
                acc[fm][fn] = __builtin_amdgcn_mfma_f32_16x16x32_bf16(al[fm], bh[fn], acc[fm][fn], 0, 0, 0);
            }
    }

    float biasc[4];
    #pragma unroll
    for (int fn = 0; fn < 4; ++fn) biasc[fn] = bias[bn + wc + fn * 16 + colL];

    #pragma unroll
    for (int fm = 0; fm < 4; ++fm) {
        #pragma unroll
        for (int fn = 0; fn < 4; ++fn) {
            const int gc = bn + wc + fn * 16 + colL;
            #pragma unroll
            for (int r = 0; r < 4; ++r) {
                const int gr = bm + wr + fm * 16 + rowL + r;
                float o = acc[fm][fn][r] + biasc[fn];
                if (MODE == SM_SWISH) {
                    float s = o / (1.f + expf(-o));
                    u16 h, l; split2(s, h, l);
                    o2[(size_t)gr * N + gc] = h;
                    o3[(size_t)gr * N + gc] = l;
                } else if (MODE == SM_RESHALF_F32) {
                    o1[(size_t)gr * N + gc] = res[(size_t)gr * N + gc] + 0.5f * o;
                } else if (MODE == SM_RESHALF_SPLIT) {
                    float v = res[(size_t)gr * N + gc] + 0.5f * o;
                    u16 h, l; split2(v, h, l);
                    o2[(size_t)gr * N + gc] = h;
                    o3[(size_t)gr * N + gc] = l;
                } else if (MODE == SM_Q) {
                    const int b_ = gr >> 6, i_ = gr & 63, h_ = gc >> 7, d_ = gc & 127;
                    const size_t idx = (((size_t)(b_ * HEADS + h_) * NN + i_) << 7) + d_;
                    u16 h, l; split2(o, h, l);
                    o2[idx] = h; o3[idx] = l;
                } else if (MODE == SM_KV) {
                    const int grow = row0 + gr;
                    const int b_ = grow >> 11, j_ = grow & 2047;
                    if (gc < DIMM) {
                        const int h_ = gc >> 7, d_ = gc & 127;
                        const size_t idx = (((size_t)(b_ * HEADS + h_) * JJ + j_) << 7) + d_;
                        u16 h, l; split2(o, h, l);
                        o2[idx] = h; o3[idx] = l;
                    } else {
                        const int cc2 = gc - DIMM;
                        const int h_ = cc2 >> 7, d_ = cc2 & 127;
                        o4[((size_t)(b_ * HEADS + h_) * DH + d_) * JJ + j_] = bf16rne(o);
                    }
                } else {  // SM_RESBIAS
                    o1[(size_t)gr * N + gc] = res[(size_t)gr * N + gc] + o;
                }
            }
        }
    }
}

// ---------------- dots = scale * Q @ K^T (3-term split MFMA) ----------------
__global__ __launch_bounds__(256, 2) void dmfma_k(
    const u16* __restrict__ Qh, const u16* __restrict__ Ql,
    const u16* __restrict__ Kh, const u16* __restrict__ Kl,
    float* __restrict__ dots)
{
    __shared__ u16 sQh[64 * 32], sQl[64 * 32], sKh[128 * 32], sKl[128 * 32];

    const int tid  = threadIdx.x;
    const int bh   = blockIdx.y;
    const int jt   = blockIdx.x * 128;
    const int lane = tid & 63;
    const int wid  = tid >> 6;
    const int wr   = (wid >> 1) * 32;
    const int wc   = (wid & 1) * 64;
    const int colL = lane & 15;
    const int rowL = (lane >> 4) * 4;
    const int kL   = (lane >> 4) * 8;
    const int srow = lane >> 2;
    const int skc  = (lane & 3) * 8;

    const size_t qbase = (size_t)bh * NN * DH;
    const size_t kbase = (size_t)bh * JJ * DH;

    const f32x4 z4 = {0.f, 0.f, 0.f, 0.f};
    f32x4 acc[2][4];
    #pragma unroll
    for (int i = 0; i < 2; ++i)
        #pragma unroll
        for (int j = 0; j < 4; ++j) acc[i][j] = z4;

    for (int d0 = 0; d0 < DH; d0 += 32) {
        __syncthreads();
        {
            const size_t gq = qbase + (size_t)(wid * 16 + srow) * DH + d0 + skc;
            gload16(&Qh[gq], &sQh[wid * 512]);
            gload16(&Ql[gq], &sQl[wid * 512]);
        }
        #pragma unroll
        for (int ss = 0; ss < 2; ++ss) {
            const int s = wid * 2 + ss;
            const size_t gk = kbase + (size_t)(jt + s * 16 + srow) * DH + d0 + skc;
            gload16(&Kh[gk], &sKh[s * 512]);
            gload16(&Kl[gk], &sKl[s * 512]);
        }
        __syncthreads();

        short8 qh[2], ql[2], kh[4], kl[4];
        #pragma unroll
        for (int f = 0; f < 2; ++f) {
            const int ra = (wr + f * 16 + colL) * 32 + kL;
            qh[f] = *(const short8*)&sQh[ra];
            ql[f] = *(const short8*)&sQl[ra];
        }
        #pragma unroll
        for (int f = 0; f < 4; ++f) {
            const int rb = (wc + f * 16 + colL) * 32 + kL;
            kh[f] = *(const short8*)&sKh[rb];
            kl[f] = *(const short8*)&sKl[rb];
        }
        #pragma unroll
        for (int fm = 0; fm < 2; ++fm)
            #pragma unroll
            for (int fn = 0; fn < 4; ++fn) {
                acc[fm][fn] = __builtin_amdgcn_mfma_f32_16x16x32_bf16(qh[fm], kh[fn], acc[fm][fn], 0, 0, 0);
                acc[fm][fn] = __builtin_amdgcn_mfma_f32_16x16x32_bf16(qh[fm], kl[fn], acc[fm][fn], 0, 0, 0);
                acc[fm][fn] = __builtin_amdgcn_mfma_f32_16x16x32_bf16(ql[fm], kh[fn], acc[fm][fn], 0, 0, 0);
            }
    }

    const float scl = 0.08838834764831845f;
    #pragma unroll
    for (int fm = 0; fm < 2; ++fm)
        #pragma unroll
        for (int fn = 0; fn < 4; ++fn)
            #pragma unroll
            for (int r = 0; r < 4; ++r) {
                const int qi = wr + fm * 16 + rowL + r;
                const int jc = jt + wc + fn * 16 + colL;
                dots[((size_t)bh * NN + qi) * JJ + jc] = acc[fm][fn][r] * scl;
            }
}

// ---------------- top-k + masked softmax; emits P as bf16 IN-PLACE ----------------
__global__ __launch_bounds__(256) void topk_sm_k(float* __restrict__ dots)
{
    const int wid  = threadIdx.x >> 6;
    const int lane = threadIdx.x & 63;
    const int r = blockIdx.x * 4 + wid;
    const int b = r >> 8;
    const int h = (r >> 6) & 3;
    float* row = dots + (size_t)r * JJ;

    float d[32];
    unsigned key[32];
    #pragma unroll
    for (int t = 0; t < 32; ++t) {
        d[t] = row[lane + 64 * t];
        key[t] = fkey(d[t]);
    }

    unsigned cur = 0u;
    for (int bit = 31; bit >= 0; --bit) {
        const unsigned cand = cur | (1u << bit);
        int c = 0;
        #pragma unroll
        for (int t = 0; t < 32; ++t) c += (key[t] >= cand) ? 1 : 0;
        c = wred_sumi(c);
        if (c >= TOPKK) cur = cand;
    }

    const int LB = (h == 0) ? 1 : (h == 1) ? 4 : (h == 2) ? 8 : 1000;
    float m = -FLTMAXF;
    #pragma unroll
    for (int t = 0; t < 32; ++t) {
        const int j = lane + 64 * t;
        int df = (j >> 6) - b; df = (df < 0) ? -df : df;
        const bool keep = (df <= LB) && (key[t] >= cur);
        d[t] = keep ? d[t] : -FLTMAXF;
        m = fmaxf(m, d[t]);
    }
    m = wred_max(m);

    float s = 0.f;
    float e[32];
    #pragma unroll
    for (int t = 0; t < 32; ++t) {
        e[t] = expf(d[t] - m);
        s += e[t];
    }
    s = wred_sum(s);
    const float inv = 1.0f / s;

    u16* prow = (u16*)row;
    #pragma unroll
    for (int t = 0; t < 32; ++t) prow[lane + 64 * t] = bf16rne(e[t] * inv);
}

// ---------------- attn = P @ V^T-layout (bf16 MFMA, 1-term) ----------------
__global__ __launch_bounds__(256, 2) void pvm_k(
    const u16* __restrict__ Pb,     // [bh][i][j], row pitch 2*JJ u16 (in dots buffer)
    const u16* __restrict__ Vt,     // [bh][d][j]
    u16* __restrict__ attnh, u16* __restrict__ attnl)
{
    __shared__ u16 sP[64 * 32], sVt[128 * 32];

    const int tid  = threadIdx.x;
    const int bh   = blockIdx.x;
    const int lane = tid & 63;
    const int wid  = tid >> 6;
    const int wr   = (wid >> 1) * 32;
    const int wc   = (wid & 1) * 64;
    const int colL = lane & 15;
    const int rowL = (lane >> 4) * 4;
    const int kL   = (lane >> 4) * 8;
    const int srow = lane >> 2;
    const int skc  = (lane & 3) * 8;

    const size_t pbase = (size_t)bh * NN * (2 * JJ);
    const size_t vbase = (size_t)bh * DH * JJ;

    const f32x4 z4 = {0.f, 0.f, 0.f, 0.f};
    f32x4 acc[2][4];
    #pragma unroll
    for (int i = 0; i < 2; ++i)
        #pragma unroll
        for (int j = 0; j < 4; ++j) acc[i][j] = z4;

    for (int j0 = 0; j0 < JJ; j0 += 32) {
        __syncthreads();
        {
            const size_t gp = pbase + (size_t)(wid * 16 + srow) * (2 * JJ) + j0 + skc;
            gload16(&Pb[gp], &sP[wid * 512]);
        }
        #pragma unroll
        for (int ss = 0; ss < 2; ++ss) {
            const int s = wid * 2 + ss;
            const size_t gv = vbase + (size_t)(s * 16 + srow) * JJ + j0 + skc;
            gload16(&Vt[gv], &sVt[s * 512]);
        }
        __syncthreads();

        short8 pf[2], vf[4];
        #pragma unroll
        for (int f = 0; f < 2; ++f)
            pf[f] = *(const short8*)&sP[(wr + f * 16 + colL) * 32 + kL];
        #pragma unroll
        for (int f = 0; f < 4; ++f)
            vf[f] = *(const short8*)&sVt[(wc + f * 16 + colL) * 32 + kL];
        #pragma unroll
        for (int fm = 0; fm < 2; ++fm)
            #pragma unroll
            for (int fn = 0; fn < 4; ++fn)
                acc[fm][fn] = __builtin_amdgcn_mfma_f32_16x16x32_bf16(pf[fm], vf[fn], acc[fm][fn], 0, 0, 0);
    }

    const int b = bh >> 2, h = bh & 3;
    #pragma unroll
    for (int fm = 0; fm < 2; ++fm)
        #pragma unroll
        for (int fn = 0; fn < 4; ++fn)
            #pragma unroll
            for (int r = 0; r < 4; ++r) {
                const int i = wr + fm * 16 + rowL + r;
                const int dcol = wc + fn * 16 + colL;
                const size_t idx = (size_t)(b * NN + i) * DIMM + h * DH + dcol;
                u16 hh, ll; split2(acc[fm][fn][r], hh, ll);
                attnh[idx] = hh; attnl[idx] = ll;
            }
}

// ---------------- host ----------------
extern "C" void kernel_launch(void* const* d_in, const int* in_sizes, int n_in,
                              void* d_out, int out_size, void* d_ws, size_t ws_size,
                              hipStream_t stream)
{
    if (ws_size < WS_WORDS_REQ * 4ull) return;   // OOB guard

    const float* x       = (const float*)d_in[0];
    const float* ctx     = (const float*)d_in[1];
    const float* ff1_w1  = (const float*)d_in[2];
    const float* ff1_b1  = (const float*)d_in[3];
    const float* ff1_w2  = (const float*)d_in[4];
    const float* ff1_b2  = (const float*)d_in[5];
    const float* ffkv_w1 = (const float*)d_in[6];
    const float* ffkv_b1 = (const float*)d_in[7];
    const float* ffkv_w2 = (const float*)d_in[8];
    const float* ffkv_b2 = (const float*)d_in[9];
    const float* wq      = (const float*)d_in[10];
    const float* bq      = (const float*)d_in[11];
    const float* wkv     = (const float*)d_in[12];
    const float* bkv     = (const float*)d_in[13];
    const float* wo      = (const float*)d_in[14];
    const float* bo      = (const float*)d_in[15];
    const float* ln1_g   = (const float*)d_in[16];
    const float* ln1_b   = (const float*)d_in[17];
    const float* lnkv_g  = (const float*)d_in[18];
    const float* lnkv_b  = (const float*)d_in[19];
    const float* lna_g   = (const float*)d_in[20];
    const float* lna_b   = (const float*)d_in[21];
    const float* lnf_g   = (const float*)d_in[22];
    const float* lnf_b   = (const float*)d_in[23];

    float* ws = (float*)d_ws;
    // word layout (82,837,504 words = 331.4 MB):
    // [0 .. 1M)        : Q split (Qh,Ql) u16 -> reused as attn split after dots
    // [1M .. 34.5M)    : K split (Khi, Klo) u16
    // [34.5M .. 51.3M) : Vt bf16 [bh][d][j]
    // [51.3M .. 52.4M) : x1 f32
    // [52.4M .. 57.7M) : weight splits
    // [57.7M .. 82.8M) : union R (25.17M words: chunk scratch / dots / x2)
    u16*   Qhs = (u16*)ws;
    u16*   Qls = Qhs + 1048576;
    u16*   Khs = (u16*)(ws + 1048576);
    u16*   Kls = Khs + 33554432;
    u16*   Vt  = (u16*)(ws + 34603008);
    float* x1  = ws + 51380224;
    float* wsp = x1 + 1048576;
    float* R   = wsp + 5242880;

    u16* w1Th  = (u16*)wsp;
    u16* w1Tl  = w1Th  + 1048576;
    u16* w2Th  = w1Tl  + 1048576;
    u16* w2Tl  = w2Th  + 1048576;
    u16* kw1Th = w2Tl  + 1048576;
    u16* kw1Tl = kw1Th + 1048576;
    u16* kw2Th = kw1Tl + 1048576;
    u16* kw2Tl = kw2Th + 1048576;
    u16* wqTh  = kw2Tl + 1048576;
    u16* wqTl  = wqTh  + 262144;
    u16* wkvTh = wqTl  + 262144;
    u16* wkvTl = wkvTh + 524288;
    u16* woTh  = wkvTl + 524288;
    u16* woTl  = woTh  + 262144;

    // R overlays (temporally disjoint):
    u16* lnxh  = (u16*)R;                       // x path
    u16* lnxl  = lnxh  + 1048576;
    u16* hxh   = lnxl  + 1048576;
    u16* hxl   = hxh   + 4194304;
    u16* lnx2h = hxl   + 4194304;
    u16* lnx2l = lnx2h + 1048576;
    u16* lnch  = (u16*)R;                       // context chunks (CH=8192)
    u16* lncl  = lnch  + 4194304;               // [8192][512] each
    u16* hch   = lncl  + 4194304;               // [8192][2048] each
    u16* hcl   = hch   + 16777216;
    u16* ctxnh = hcl   + 16777216;              // [8192][512] each
    u16* ctxnl = ctxnh + 4194304;
    float* dots = R;                            // [8192][2048] f32; P bf16 in-place
    float* x2   = R;                            // after P dead
    u16* attnh  = (u16*)ws;                     // over dead Q split
    u16* attnl  = attnh + 1048576;

    // ---- weight transpose+split ----
    wsplit_k<<<dim3(FFD / 64, DIMM / 64), 256, 0, stream>>>(ff1_w1,  w1Th,  w1Tl,  DIMM, FFD);
    wsplit_k<<<dim3(DIMM / 64, FFD / 64), 256, 0, stream>>>(ff1_w2,  w2Th,  w2Tl,  FFD,  DIMM);
    wsplit_k<<<dim3(FFD / 64, DIMM / 64), 256, 0, stream>>>(ffkv_w1, kw1Th, kw1Tl, DIMM, FFD);
    wsplit_k<<<dim3(DIMM / 64, FFD / 64), 256, 0, stream>>>(ffkv_w2, kw2Th, kw2Tl, FFD,  DIMM);
    wsplit_k<<<dim3(DIMM / 64, DIMM / 64), 256, 0, stream>>>(wq,     wqTh,  wqTl,  DIMM, DIMM);
    wsplit_k<<<dim3(1024 / 64, DIMM / 64), 256, 0, stream>>>(wkv,    wkvTh, wkvTl, DIMM, 1024);
    wsplit_k<<<dim3(DIMM / 64, DIMM / 64), 256, 0, stream>>>(wo,     woTh,  woTl,  DIMM, DIMM);

    // ---- x path ----
    ln_split_k<<<RX / 4, 256, 0, stream>>>(x, ln1_g, ln1_b, lnxh, lnxl);
    mgemm_k<SM_SWISH><<<dim3(FFD / 128, RX / 128), 256, 0, stream>>>(
        lnxh, lnxl, w1Th, w1Tl, ff1_b1, nullptr, nullptr, hxh, hxl, nullptr, FFD, DIMM, 0);
    mgemm_k<SM_RESHALF_F32><<<dim3(DIMM / 128, RX / 128), 256, 0, stream>>>(
        hxh, hxl, w2Th, w2Tl, ff1_b2, x, x1, nullptr, nullptr, nullptr, DIMM, FFD, 0);
    ln_split_k<<<RX / 4, 256, 0, stream>>>(x1, lna_g, lna_b, lnx2h, lnx2l);
    mgemm_k<SM_Q><<<dim3(DIMM / 128, RX / 128), 256, 0, stream>>>(
        lnx2h, lnx2l, wqTh, wqTl, bq, nullptr, nullptr, Qhs, Qls, nullptr, DIMM, DIMM, 0);

    // ---- context chunks (CH=8192, NCH=8) ----
    for (int c = 0; c < NCH; ++c) {
        const float* cptr = ctx + (size_t)c * CH * DIMM;
        ln_split_k<<<CH / 4, 256, 0, stream>>>(cptr, lnkv_g, lnkv_b, lnch, lncl);
        mgemm_k<SM_SWISH><<<dim3(FFD / 128, CH / 128), 256, 0, stream>>>(
            lnch, lncl, kw1Th, kw1Tl, ffkv_b1, nullptr, nullptr, hch, hcl, nullptr, FFD, DIMM, 0);
        mgemm_k<SM_RESHALF_SPLIT><<<dim3(DIMM / 128, CH / 128), 256, 0, stream>>>(
            hch, hcl, kw2Th, kw2Tl, ffkv_b2, cptr, nullptr, ctxnh, ctxnl, nullptr, DIMM, FFD, 0);
        mgemm_k<SM_KV><<<dim3(1024 / 128, CH / 128), 256, 0, stream>>>(
            ctxnh, ctxnl, wkvTh, wkvTl, bkv, nullptr, nullptr, Khs, Kls, Vt, 1024, DIMM, c * CH);
    }

    // ---- attention ----
    dmfma_k<<<dim3(JJ / 128, BB * HEADS), 256, 0, stream>>>(Qhs, Qls, Khs, Kls, dots);
    topk_sm_k<<<(BB * HEADS * NN) / 4, 256, 0, stream>>>(dots);
    pvm_k<<<BB * HEADS, 256, 0, stream>>>((const u16*)dots, Vt, attnh, attnl);

    // ---- output projection + residual + final LN ----
    mgemm_k<SM_RESBIAS><<<dim3(DIMM / 128, RX / 128), 256, 0, stream>>>(
        attnh, attnl, woTh, woTl, bo, x1, x2, nullptr, nullptr, nullptr, DIMM, DIMM, 0);
    ln_k<<<RX / 4, 256, 0, stream>>>(x2, lnf_g, lnf_b, (float*)d_out);
}